// Round 7
// baseline (662.689 us; speedup 1.0000x reference)
//
#include <hip/hip_runtime.h>
#include <hip/hip_cooperative_groups.h>
#include <hip/hip_fp16.h>
#include <math.h>

namespace cg = cooperative_groups;

// GAE: 2x GCNConv + edge dot decode.
// R1-R10: bucketed CSR build, fp16 tables, wide gathers, MFMA mms,
//         4 nodes/wave gather convs.  (best: 228.2us)
// R11 FAILED: LDS decode latency-bound. R12/R14 NEUTRAL: build reshapes.
// R13/R15 MEASUREMENT: warm ledger mm1~19(->10 R16), conv1~25, mm2~2.5,
//      conv2~16, decode~16, build~10 + per-dispatch overhead ~7-15us.
// R16 ~NEUTRAL (226.2): mm1 -9us kernel time -> total -1.2us. Third time a
//      kernel reduction failed to reach the total while additions show 1:1
//      => per-dispatch floor dominates. 8 dispatches ~ 50-60us of overhead.
// R17: ONE cooperative mega-kernel (hipLaunchCooperativeKernel) with
//      grid.sync() between the 8 phases; per-phase bodies are verbatim
//      ports (bit-identical math). Grid sized via occupancy API (deadlock-
//      safe). Legacy 8-kernel path kept as runtime fallback if cooperative
//      capture is rejected.

#define NBMAX 512    // max buckets (supports N <= 131072 at 256/bucket)
#define BSHIFT 8     // 256 nodes per bucket
#define BNODES 256
#define CHF 16384    // edges per partition virtual-block (98 at E=1.6M)
#define CAPSHIFT 13  // 8192 edge slots per bucket
#define CAP (1 << CAPSHIFT)

typedef _Float16 half8 __attribute__((ext_vector_type(8)));
typedef float floatx4 __attribute__((ext_vector_type(4)));

static inline int divup(int a, int b) { return (a + b - 1) / b; }

__device__ inline void acc8(__half2* a, float4 v) {
    const __half2* h = (const __half2*)&v;
    a[0] = __hadd2(a[0], h[0]);
    a[1] = __hadd2(a[1], h[1]);
    a[2] = __hadd2(a[2], h[2]);
    a[3] = __hadd2(a[3], h[3]);
}
__device__ inline unsigned short f2bf(float f) {
    unsigned u = __builtin_bit_cast(unsigned, f);
    u = (u + 0x7FFFu + ((u >> 16) & 1u)) >> 16;
    return (unsigned short)u;
}
__device__ inline float bfdot8(uint4 a, uint4 b) {
    const unsigned* pa = (const unsigned*)&a;
    const unsigned* pb = (const unsigned*)&b;
    float v = 0.f;
#pragma unroll
    for (int w = 0; w < 4; w++) {
        float alo = __builtin_bit_cast(float, pa[w] << 16);
        float ahi = __builtin_bit_cast(float, pa[w] & 0xFFFF0000u);
        float blo = __builtin_bit_cast(float, pb[w] << 16);
        float bhi = __builtin_bit_cast(float, pb[w] & 0xFFFF0000u);
        v += alo * blo + ahi * bhi;
    }
    return v;
}

// ======================= fused cooperative kernel ===========================

struct GP {
    const float* x; const float* W1; const float* b1;
    const float* W2; const float* b2;
    const int* src; const int* tgt;
    int* gcur; unsigned* ebuf; int* col; int* rowbeg; int* rowend; float* dinv;
    __half* hs; __half* h2; __half* zs; unsigned short* zh;
    float* zout; float* recon;
    int n, e, nb, npart;
};

__global__ __launch_bounds__(256) void k_fused(GP p) {
    cg::grid_group grid = cg::this_grid();
    __shared__ union {
        struct { int h[NBMAX]; int base[NBMAX]; } pt;        // 4KB
        struct { int cnt[BNODES]; int scan[BNODES]; int cur[BNODES]; } bf; // 3KB
        _Float16 wt1[64 * 136];                              // 17408B
        _Float16 wt2[32 * 72];                               // 4608B
    } sm;
    const int tid = threadIdx.x;
    const int nblk = gridDim.x;

    // ---- P0: init bucket cursors + zero pad rows ----
    if (blockIdx.x == 0) {
        for (int b = tid; b < NBMAX; b += 256) p.gcur[b] = b << CAPSHIFT;
        unsigned* hp = (unsigned*)(p.hs + (size_t)p.n * 64);
        unsigned* zp = (unsigned*)(p.zs + (size_t)p.n * 32);
        if (tid < 32) hp[tid] = 0;
        else if (tid < 48) zp[tid - 32] = 0;
    }
    grid.sync();

    // ---- P1: partition edges (two-pass per virtual block) ----
    for (int vb = blockIdx.x; vb < p.npart; vb += nblk) {
        __syncthreads();
        int e0 = vb * CHF;
        for (int b = tid; b < p.nb; b += 256) sm.pt.h[b] = 0;
        __syncthreads();
        for (int r = 0; r < 16; r++) {
            int e = e0 + (r * 256 + tid) * 4;
            if (e + 3 < p.e) {
                int4 t4 = *(const int4*)(p.tgt + e);
                atomicAdd(&sm.pt.h[t4.x >> BSHIFT], 1);
                atomicAdd(&sm.pt.h[t4.y >> BSHIFT], 1);
                atomicAdd(&sm.pt.h[t4.z >> BSHIFT], 1);
                atomicAdd(&sm.pt.h[t4.w >> BSHIFT], 1);
            } else {
                for (int j = 0; j < 4; j++) {
                    int ee = e + j;
                    if (ee < p.e) atomicAdd(&sm.pt.h[p.tgt[ee] >> BSHIFT], 1);
                }
            }
        }
        __syncthreads();
        for (int b = tid; b < p.nb; b += 256) {
            int c = sm.pt.h[b];
            sm.pt.base[b] = c ? atomicAdd(&p.gcur[b], c) : 0;
        }
        __syncthreads();
        for (int r = 0; r < 16; r++) {
            int e = e0 + (r * 256 + tid) * 4;
            if (e + 3 < p.e) {
                int4 t4 = *(const int4*)(p.tgt + e);
                int4 s4 = *(const int4*)(p.src + e);
                int tv[4] = {t4.x, t4.y, t4.z, t4.w};
                int sw[4] = {s4.x, s4.y, s4.z, s4.w};
#pragma unroll
                for (int j = 0; j < 4; j++) {
                    int t = tv[j];
                    int pos = atomicAdd(&sm.pt.base[t >> BSHIFT], 1);
                    p.ebuf[pos] = ((unsigned)(t & (BNODES - 1)) << 23) | (unsigned)sw[j];
                }
            } else {
                for (int j = 0; j < 4; j++) {
                    int ee = e + j;
                    if (ee < p.e) {
                        int t = p.tgt[ee];
                        int pos = atomicAdd(&sm.pt.base[t >> BSHIFT], 1);
                        p.ebuf[pos] = ((unsigned)(t & (BNODES - 1)) << 23) | (unsigned)p.src[ee];
                    }
                }
            }
        }
    }
    grid.sync();

    // ---- P2: per-bucket CSR fill ----
    for (int vb = blockIdx.x; vb < p.nb; vb += nblk) {
        __syncthreads();
        int nbase = vb << BSHIFT;
        int ebase = vb << CAPSHIFT;
        int eend = p.gcur[vb];
        sm.bf.cnt[tid] = 0;
        __syncthreads();
        for (int e = ebase + tid; e < eend; e += BNODES) {
            atomicAdd(&sm.bf.cnt[p.ebuf[e] >> 23], 1);
        }
        __syncthreads();
        sm.bf.scan[tid] = sm.bf.cnt[tid];
        __syncthreads();
        for (int off = 1; off < BNODES; off <<= 1) {
            int t = (tid >= off) ? sm.bf.scan[tid - off] : 0;
            __syncthreads();
            sm.bf.scan[tid] += t;
            __syncthreads();
        }
        int excl = sm.bf.scan[tid] - sm.bf.cnt[tid];
        sm.bf.cur[tid] = excl;
        int node = nbase + tid;
        if (node < p.n) {
            p.rowbeg[node] = ebase + excl;
            p.rowend[node] = ebase + excl + sm.bf.cnt[tid];
            p.dinv[node] = rsqrtf((float)(sm.bf.cnt[tid] + 1));  // +1 self-loop
        }
        __syncthreads();
        for (int e = ebase + tid; e < eend; e += BNODES) {
            unsigned q = p.ebuf[e];
            int pos = atomicAdd(&sm.bf.cur[q >> 23], 1);
            p.col[ebase + pos] = (int)(q & 0x7FFFFFu);
        }
    }
    grid.sync();

    // ---- P3: mm1 (A direct global->reg, Wt1 staged once per block) ----
    {
#pragma unroll
        for (int i = 0; i < 16; i++) {
            int f = tid + i * 256;          // 0..4095
            int c = f & 63, kp = f >> 6;    // kp 0..63 (pairs of k)
            float a = p.W1[(size_t)(2 * kp) * 64 + c];
            float b = p.W1[(size_t)(2 * kp + 1) * 64 + c];
            *(__half2*)&sm.wt1[c * 136 + 2 * kp] = __floats2half2_rn(a, b);
        }
        __syncthreads();
        int w = tid >> 6, lane = tid & 63;
        int quad = lane >> 4, m = lane & 15;
        int ntile = (p.n + 63) >> 6;
        for (int vt = blockIdx.x; vt < ntile; vt += nblk) {
            int nbase = vt * 64;
            int arow = nbase + w * 16 + m;
            const float* xb = p.x + (size_t)(arow < p.n ? arow : p.n - 1) * 128;
            floatx4 acc[4] = {{0.f, 0.f, 0.f, 0.f}, {0.f, 0.f, 0.f, 0.f},
                              {0.f, 0.f, 0.f, 0.f}, {0.f, 0.f, 0.f, 0.f}};
#pragma unroll
            for (int kt = 0; kt < 4; kt++) {
                float4 v0 = *(const float4*)(xb + kt * 32 + quad * 8);
                float4 v1 = *(const float4*)(xb + kt * 32 + quad * 8 + 4);
                union { half8 h8; __half2 h2[4]; } ua;
                ua.h2[0] = __floats2half2_rn(v0.x, v0.y);
                ua.h2[1] = __floats2half2_rn(v0.z, v0.w);
                ua.h2[2] = __floats2half2_rn(v1.x, v1.y);
                ua.h2[3] = __floats2half2_rn(v1.z, v1.w);
#pragma unroll
                for (int ct = 0; ct < 4; ct++) {
                    half8 b = *(const half8*)&sm.wt1[(ct * 16 + m) * 136 + kt * 32 + quad * 8];
                    acc[ct] = __builtin_amdgcn_mfma_f32_16x16x32_f16(ua.h8, b, acc[ct], 0, 0, 0);
                }
            }
#pragma unroll
            for (int reg = 0; reg < 4; reg++) {
                int node = nbase + w * 16 + quad * 4 + reg;
                if (node < p.n) {
                    float d = p.dinv[node];
#pragma unroll
                    for (int ct = 0; ct < 4; ct++) {
                        p.hs[(size_t)node * 64 + ct * 16 + m] = __float2half(acc[ct][reg] * d);
                    }
                }
            }
        }
    }
    grid.sync();

    // ---- P4: conv1 (4 nodes/wave, 8 feat lanes x 2 edge slots) ----
    {
        int wid = (blockIdx.x * 256 + tid) >> 6;
        int wstride = (nblk * 256) >> 6;
        int lane = tid & 63;
        int q = lane >> 4, ln = lane & 15, qb = q << 4;
        int el = ln >> 3, fl = ln & 7;
        for (int gw = wid; gw * 4 < p.n; gw += wstride) {
            int w = gw * 4 + q;
            if (w < p.n) {
                int beg = p.rowbeg[w], end = p.rowend[w];
                int deg = end - beg;
                int m = min(16, deg);
                int m2 = min(16, deg - 16);
                int sl = (ln < m) ? p.col[beg + ln] : 0;
                int sl2 = (ln < m2) ? p.col[beg + 16 + ln] : 0;
                __half2 a2[4];
#pragma unroll
                for (int j = 0; j < 4; j++) a2[j] = __half2half2(__float2half(0.f));
                int rs = (el == 0) ? w : p.n;
                float4 S = *(const float4*)(p.hs + (size_t)rs * 64 + fl * 8);
                float4 L[4];
#pragma unroll
                for (int r = 0; r < 4; r++) {
                    int idx = 2 * r + el;
                    int s = __shfl(sl, qb + idx);
                    int a = (idx < m) ? s : p.n;
                    L[r] = *(const float4*)(p.hs + (size_t)a * 64 + fl * 8);
                }
                acc8(a2, S);
#pragma unroll
                for (int r = 0; r < 4; r++) acc8(a2, L[r]);
#pragma unroll
                for (int r = 0; r < 4; r++) {
                    int idx = 8 + 2 * r + el;
                    int s = __shfl(sl, qb + idx);
                    int a = (idx < m) ? s : p.n;
                    L[r] = *(const float4*)(p.hs + (size_t)a * 64 + fl * 8);
                }
#pragma unroll
                for (int r = 0; r < 4; r++) acc8(a2, L[r]);
                if (deg > 16) {
#pragma unroll
                    for (int r = 0; r < 4; r++) {
                        int idx = 2 * r + el;
                        int s = __shfl(sl2, qb + idx);
                        int a = (idx < m2) ? s : p.n;
                        L[r] = *(const float4*)(p.hs + (size_t)a * 64 + fl * 8);
                    }
#pragma unroll
                    for (int r = 0; r < 4; r++) acc8(a2, L[r]);
#pragma unroll
                    for (int r = 0; r < 4; r++) {
                        int idx = 8 + 2 * r + el;
                        int s = __shfl(sl2, qb + idx);
                        int a = (idx < m2) ? s : p.n;
                        L[r] = *(const float4*)(p.hs + (size_t)a * 64 + fl * 8);
                    }
#pragma unroll
                    for (int r = 0; r < 4; r++) acc8(a2, L[r]);
                }
                if (deg > 32) {
                    for (int b0 = 32; b0 < deg; b0 += 16) {
                        int mc = min(16, deg - b0);
                        int sl3 = (ln < mc) ? p.col[beg + b0 + ln] : 0;
                        for (int r = 0; r < 8; r++) {
                            int idx = 2 * r + el;
                            int s = __shfl(sl3, qb + idx);
                            int a = (idx < mc) ? s : p.n;
                            float4 v = *(const float4*)(p.hs + (size_t)a * 64 + fl * 8);
                            acc8(a2, v);
                        }
                    }
                }
                float r[8];
#pragma unroll
                for (int j = 0; j < 4; j++) {
                    float2 f = __half22float2(a2[j]);
                    r[2 * j] = f.x;
                    r[2 * j + 1] = f.y;
                }
#pragma unroll
                for (int j = 0; j < 8; j++) r[j] += __shfl_xor(r[j], 8);
                if (el == 0) {
                    float d = p.dinv[w];
                    float4 bb0 = *(const float4*)(p.b1 + fl * 8);
                    float4 bb1 = *(const float4*)(p.b1 + fl * 8 + 4);
                    union { float4 f; __half2 h[4]; } u;
                    u.h[0] = __floats2half2_rn(fmaxf(r[0] * d + bb0.x, 0.f),
                                               fmaxf(r[1] * d + bb0.y, 0.f));
                    u.h[1] = __floats2half2_rn(fmaxf(r[2] * d + bb0.z, 0.f),
                                               fmaxf(r[3] * d + bb0.w, 0.f));
                    u.h[2] = __floats2half2_rn(fmaxf(r[4] * d + bb1.x, 0.f),
                                               fmaxf(r[5] * d + bb1.y, 0.f));
                    u.h[3] = __floats2half2_rn(fmaxf(r[6] * d + bb1.z, 0.f),
                                               fmaxf(r[7] * d + bb1.w, 0.f));
                    *(float4*)(p.h2 + (size_t)w * 64 + fl * 8) = u.f;
                }
            }
        }
    }
    grid.sync();

    // ---- P5: mm2 ----
    {
#pragma unroll
        for (int i = 0; i < 4; i++) {
            int f = tid + i * 256;          // 0..1023
            int c = f & 31, kp = f >> 5;
            float a = p.W2[(size_t)(2 * kp) * 32 + c];
            float b = p.W2[(size_t)(2 * kp + 1) * 32 + c];
            *(__half2*)&sm.wt2[c * 72 + 2 * kp] = __floats2half2_rn(a, b);
        }
        __syncthreads();
        int w = tid >> 6, lane = tid & 63;
        int quad = lane >> 4, m = lane & 15;
        int ntile = (p.n + 63) >> 6;
        for (int vt = blockIdx.x; vt < ntile; vt += nblk) {
            int nbase = vt * 64;
            int arow = nbase + w * 16 + m;
            const __half* abase = p.h2 + (size_t)(arow < p.n ? arow : p.n - 1) * 64;
            floatx4 acc[2] = {{0.f, 0.f, 0.f, 0.f}, {0.f, 0.f, 0.f, 0.f}};
#pragma unroll
            for (int kt = 0; kt < 2; kt++) {
                half8 a = *(const half8*)(abase + kt * 32 + quad * 8);
#pragma unroll
                for (int ct = 0; ct < 2; ct++) {
                    half8 b = *(const half8*)&sm.wt2[(ct * 16 + m) * 72 + kt * 32 + quad * 8];
                    acc[ct] = __builtin_amdgcn_mfma_f32_16x16x32_f16(a, b, acc[ct], 0, 0, 0);
                }
            }
#pragma unroll
            for (int reg = 0; reg < 4; reg++) {
                int node = nbase + w * 16 + quad * 4 + reg;
                if (node < p.n) {
                    float d = p.dinv[node];
#pragma unroll
                    for (int ct = 0; ct < 2; ct++) {
                        p.zs[(size_t)node * 32 + ct * 16 + m] = __float2half(acc[ct][reg] * d);
                    }
                }
            }
        }
    }
    grid.sync();

    // ---- P6: conv2 (4 nodes/wave, 4 feat lanes x 4 edge slots) ----
    {
        int wid = (blockIdx.x * 256 + tid) >> 6;
        int wstride = (nblk * 256) >> 6;
        int lane = tid & 63;
        int q = lane >> 4, ln = lane & 15, qb = q << 4;
        int el = ln >> 2, fl = ln & 3;
        for (int gw = wid; gw * 4 < p.n; gw += wstride) {
            int w = gw * 4 + q;
            if (w < p.n) {
                int beg = p.rowbeg[w], end = p.rowend[w];
                int deg = end - beg;
                int m = min(16, deg);
                int m2 = min(16, deg - 16);
                int sl = (ln < m) ? p.col[beg + ln] : 0;
                int sl2 = (ln < m2) ? p.col[beg + 16 + ln] : 0;
                __half2 a2[4];
#pragma unroll
                for (int j = 0; j < 4; j++) a2[j] = __half2half2(__float2half(0.f));
                int rs = (el == 0) ? w : p.n;
                float4 S = *(const float4*)(p.zs + (size_t)rs * 32 + fl * 8);
                float4 L[4];
#pragma unroll
                for (int r = 0; r < 4; r++) {
                    int idx = 4 * r + el;
                    int s = __shfl(sl, qb + idx);
                    int a = (idx < m) ? s : p.n;
                    L[r] = *(const float4*)(p.zs + (size_t)a * 32 + fl * 8);
                }
                acc8(a2, S);
#pragma unroll
                for (int r = 0; r < 4; r++) acc8(a2, L[r]);
                if (deg > 16) {
#pragma unroll
                    for (int r = 0; r < 4; r++) {
                        int idx = 4 * r + el;
                        int s = __shfl(sl2, qb + idx);
                        int a = (idx < m2) ? s : p.n;
                        L[r] = *(const float4*)(p.zs + (size_t)a * 32 + fl * 8);
                    }
#pragma unroll
                    for (int r = 0; r < 4; r++) acc8(a2, L[r]);
                }
                if (deg > 32) {
                    for (int b0 = 32; b0 < deg; b0 += 16) {
                        int mc = min(16, deg - b0);
                        int sl3 = (ln < mc) ? p.col[beg + b0 + ln] : 0;
                        for (int r = 0; r < 4; r++) {
                            int idx = 4 * r + el;
                            int s = __shfl(sl3, qb + idx);
                            int a = (idx < mc) ? s : p.n;
                            float4 v = *(const float4*)(p.zs + (size_t)a * 32 + fl * 8);
                            acc8(a2, v);
                        }
                    }
                }
                float r[8];
#pragma unroll
                for (int j = 0; j < 4; j++) {
                    float2 f = __half22float2(a2[j]);
                    r[2 * j] = f.x;
                    r[2 * j + 1] = f.y;
                }
#pragma unroll
                for (int d = 4; d < 16; d <<= 1)
#pragma unroll
                    for (int j = 0; j < 8; j++) r[j] += __shfl_xor(r[j], d);
                if (el == 0) {
                    float d = p.dinv[w];
                    float4 bb0 = *(const float4*)(p.b2 + fl * 8);
                    float4 bb1 = *(const float4*)(p.b2 + fl * 8 + 4);
                    float o0 = r[0] * d + bb0.x, o1 = r[1] * d + bb0.y;
                    float o2 = r[2] * d + bb0.z, o3 = r[3] * d + bb0.w;
                    float o4 = r[4] * d + bb1.x, o5 = r[5] * d + bb1.y;
                    float o6 = r[6] * d + bb1.z, o7 = r[7] * d + bb1.w;
                    *(float4*)(p.zout + (size_t)w * 32 + fl * 8) = make_float4(o0, o1, o2, o3);
                    *(float4*)(p.zout + (size_t)w * 32 + fl * 8 + 4) = make_float4(o4, o5, o6, o7);
                    uint4 pk;
                    pk.x = (unsigned)f2bf(o0) | ((unsigned)f2bf(o1) << 16);
                    pk.y = (unsigned)f2bf(o2) | ((unsigned)f2bf(o3) << 16);
                    pk.z = (unsigned)f2bf(o4) | ((unsigned)f2bf(o5) << 16);
                    pk.w = (unsigned)f2bf(o6) | ((unsigned)f2bf(o7) << 16);
                    *(uint4*)(p.zh + (size_t)w * 32 + fl * 8) = pk;
                }
            }
        }
    }
    grid.sync();

    // ---- P7: decode ----
    {
        int g = (blockIdx.x * 256 + tid) >> 2;
        int gstride = nblk * 64;
        int fl = tid & 3;
        for (; g * 4 < p.e; g += gstride) {
            int e0 = g * 4;
            int cnt = min(4, p.e - e0);
            int s[4], t[4];
#pragma unroll
            for (int q = 0; q < 4; q++) {
                int e = (q < cnt) ? e0 + q : e0;
                s[q] = p.src[e];
                t[q] = p.tgt[e];
            }
            uint4 Za[4], Zb[4];
#pragma unroll
            for (int q = 0; q < 4; q++) {
                Za[q] = *(const uint4*)(p.zh + (size_t)s[q] * 32 + fl * 8);
                Zb[q] = *(const uint4*)(p.zh + (size_t)t[q] * 32 + fl * 8);
            }
            float v[4];
#pragma unroll
            for (int q = 0; q < 4; q++) {
                float xv = bfdot8(Za[q], Zb[q]);
                xv += __shfl_xor(xv, 1);
                xv += __shfl_xor(xv, 2);
                v[q] = xv;
            }
            if (fl == 0) {
                if (cnt == 4) {
                    *(float4*)(p.recon + e0) = make_float4(v[0], v[1], v[2], v[3]);
                } else {
                    for (int q = 0; q < cnt; q++) p.recon[e0 + q] = v[q];
                }
            }
        }
    }
}

// ===================== legacy fallback kernels (R16) ========================

__global__ void k_init(int* __restrict__ gcur, unsigned* __restrict__ hs_pad,
                       unsigned* __restrict__ zs_pad) {
    int t = threadIdx.x;
    for (int b = t; b < NBMAX; b += 256) gcur[b] = b << CAPSHIFT;
    if (t < 32) hs_pad[t] = 0;
    else if (t < 48) zs_pad[t - 32] = 0;
}

__global__ __launch_bounds__(512) void k_part(const int* __restrict__ src,
                                              const int* __restrict__ tgt,
                                              int* __restrict__ gcur,
                                              unsigned* __restrict__ ebuf, int E, int NB) {
    __shared__ int h[NBMAX];
    __shared__ int base[NBMAX];
    int tid = threadIdx.x;
    int e0 = blockIdx.x * CHF;
    for (int b = tid; b < NB; b += 512) h[b] = 0;
    __syncthreads();
#pragma unroll
    for (int r = 0; r < 8; r++) {
        int e = e0 + (r * 512 + tid) * 4;
        if (e + 3 < E) {
            int4 t4 = *(const int4*)(tgt + e);
            atomicAdd(&h[t4.x >> BSHIFT], 1);
            atomicAdd(&h[t4.y >> BSHIFT], 1);
            atomicAdd(&h[t4.z >> BSHIFT], 1);
            atomicAdd(&h[t4.w >> BSHIFT], 1);
        } else {
            for (int j = 0; j < 4; j++) {
                int ee = e + j;
                if (ee < E) atomicAdd(&h[tgt[ee] >> BSHIFT], 1);
            }
        }
    }
    __syncthreads();
    for (int b = tid; b < NB; b += 512) {
        int c = h[b];
        base[b] = c ? atomicAdd(&gcur[b], c) : 0;
    }
    __syncthreads();
#pragma unroll
    for (int r = 0; r < 8; r++) {
        int e = e0 + (r * 512 + tid) * 4;
        if (e + 3 < E) {
            int4 t4 = *(const int4*)(tgt + e);
            int4 s4 = *(const int4*)(src + e);
            int tv[4] = {t4.x, t4.y, t4.z, t4.w};
            int sw[4] = {s4.x, s4.y, s4.z, s4.w};
#pragma unroll
            for (int j = 0; j < 4; j++) {
                int t = tv[j];
                int pos = atomicAdd(&base[t >> BSHIFT], 1);
                ebuf[pos] = ((unsigned)(t & (BNODES - 1)) << 23) | (unsigned)sw[j];
            }
        } else {
            for (int j = 0; j < 4; j++) {
                int ee = e + j;
                if (ee < E) {
                    int t = tgt[ee];
                    int pos = atomicAdd(&base[t >> BSHIFT], 1);
                    ebuf[pos] = ((unsigned)(t & (BNODES - 1)) << 23) | (unsigned)src[ee];
                }
            }
        }
    }
}

__global__ __launch_bounds__(256) void k_bfill(const unsigned* __restrict__ ebuf,
                                               const int* __restrict__ gcur,
                                               int* __restrict__ rowbeg,
                                               int* __restrict__ rowend,
                                               int* __restrict__ col,
                                               float* __restrict__ dinv, int n) {
    __shared__ int s_cnt[BNODES];
    __shared__ int s_scan[BNODES];
    __shared__ int s_cur[BNODES];
    int b = blockIdx.x, tid = threadIdx.x;
    int nbase = b << BSHIFT;
    int ebase = b << CAPSHIFT;
    int eend = gcur[b];
    s_cnt[tid] = 0;
    __syncthreads();
    for (int e = ebase + tid; e < eend; e += BNODES) {
        atomicAdd(&s_cnt[ebuf[e] >> 23], 1);
    }
    __syncthreads();
    s_scan[tid] = s_cnt[tid];
    __syncthreads();
    for (int off = 1; off < BNODES; off <<= 1) {
        int t = (tid >= off) ? s_scan[tid - off] : 0;
        __syncthreads();
        s_scan[tid] += t;
        __syncthreads();
    }
    int excl = s_scan[tid] - s_cnt[tid];
    s_cur[tid] = excl;
    int node = nbase + tid;
    if (node < n) {
        rowbeg[node] = ebase + excl;
        rowend[node] = ebase + excl + s_cnt[tid];
        dinv[node] = rsqrtf((float)(s_cnt[tid] + 1));
    }
    __syncthreads();
    for (int e = ebase + tid; e < eend; e += BNODES) {
        unsigned p = ebuf[e];
        int pos = atomicAdd(&s_cur[p >> 23], 1);
        col[ebase + pos] = (int)(p & 0x7FFFFFu);
    }
}

__global__ __launch_bounds__(512) void k_mm1(const float* __restrict__ x,
                                             const float* __restrict__ W1,
                                             const float* __restrict__ dinv,
                                             __half* __restrict__ hs, int n) {
    __shared__ _Float16 Wt[64 * 136];
    int tid = threadIdx.x;
    int nbase = blockIdx.x * 128;
#pragma unroll
    for (int i = 0; i < 8; i++) {
        int f = tid + i * 512;
        int c = f & 63, kp = f >> 6;
        float a = W1[(size_t)(2 * kp) * 64 + c];
        float b = W1[(size_t)(2 * kp + 1) * 64 + c];
        *(__half2*)&Wt[c * 136 + 2 * kp] = __floats2half2_rn(a, b);
    }
    __syncthreads();
    int w = tid >> 6, lane = tid & 63;
    int quad = lane >> 4, m = lane & 15;
    int arow = nbase + w * 16 + m;
    const float* xb = x + (size_t)min(arow, n - 1) * 128;
    floatx4 acc[4] = {{0.f, 0.f, 0.f, 0.f}, {0.f, 0.f, 0.f, 0.f},
                      {0.f, 0.f, 0.f, 0.f}, {0.f, 0.f, 0.f, 0.f}};
#pragma unroll
    for (int kt = 0; kt < 4; kt++) {
        float4 v0 = *(const float4*)(xb + kt * 32 + quad * 8);
        float4 v1 = *(const float4*)(xb + kt * 32 + quad * 8 + 4);
        union { half8 h8; __half2 h2[4]; } ua;
        ua.h2[0] = __floats2half2_rn(v0.x, v0.y);
        ua.h2[1] = __floats2half2_rn(v0.z, v0.w);
        ua.h2[2] = __floats2half2_rn(v1.x, v1.y);
        ua.h2[3] = __floats2half2_rn(v1.z, v1.w);
#pragma unroll
        for (int ct = 0; ct < 4; ct++) {
            half8 b = *(const half8*)&Wt[(ct * 16 + m) * 136 + kt * 32 + quad * 8];
            acc[ct] = __builtin_amdgcn_mfma_f32_16x16x32_f16(ua.h8, b, acc[ct], 0, 0, 0);
        }
    }
#pragma unroll
    for (int reg = 0; reg < 4; reg++) {
        int node = nbase + w * 16 + quad * 4 + reg;
        if (node < n) {
            float d = dinv[node];
#pragma unroll
            for (int ct = 0; ct < 4; ct++) {
                hs[(size_t)node * 64 + ct * 16 + m] = __float2half(acc[ct][reg] * d);
            }
        }
    }
}

__global__ __launch_bounds__(256) void k_conv1(const __half* __restrict__ hs,
                                               const int* __restrict__ rowbeg,
                                               const int* __restrict__ rowend,
                                               const int* __restrict__ col,
                                               const float* __restrict__ dinv,
                                               const float* __restrict__ b1,
                                               __half* __restrict__ h2, int n) {
    int gw = (blockIdx.x * 256 + threadIdx.x) >> 6;
    int lane = threadIdx.x & 63;
    int q = lane >> 4, ln = lane & 15;
    int w = gw * 4 + q;
    if (w >= n) return;
    int qb = q << 4;
    int el = ln >> 3, fl = ln & 7;
    int beg = rowbeg[w], end = rowend[w];
    int deg = end - beg;
    int m = min(16, deg);
    int m2 = min(16, deg - 16);
    int sl = (ln < m) ? col[beg + ln] : 0;
    int sl2 = (ln < m2) ? col[beg + 16 + ln] : 0;
    __half2 a2[4];
#pragma unroll
    for (int j = 0; j < 4; j++) a2[j] = __half2half2(__float2half(0.f));
    int rs = (el == 0) ? w : n;
    float4 S = *(const float4*)(hs + (size_t)rs * 64 + fl * 8);
    float4 L[4];
#pragma unroll
    for (int r = 0; r < 4; r++) {
        int idx = 2 * r + el;
        int s = __shfl(sl, qb + idx);
        int a = (idx < m) ? s : n;
        L[r] = *(const float4*)(hs + (size_t)a * 64 + fl * 8);
    }
    acc8(a2, S);
#pragma unroll
    for (int r = 0; r < 4; r++) acc8(a2, L[r]);
#pragma unroll
    for (int r = 0; r < 4; r++) {
        int idx = 8 + 2 * r + el;
        int s = __shfl(sl, qb + idx);
        int a = (idx < m) ? s : n;
        L[r] = *(const float4*)(hs + (size_t)a * 64 + fl * 8);
    }
#pragma unroll
    for (int r = 0; r < 4; r++) acc8(a2, L[r]);
    if (deg > 16) {
#pragma unroll
        for (int r = 0; r < 4; r++) {
            int idx = 2 * r + el;
            int s = __shfl(sl2, qb + idx);
            int a = (idx < m2) ? s : n;
            L[r] = *(const float4*)(hs + (size_t)a * 64 + fl * 8);
        }
#pragma unroll
        for (int r = 0; r < 4; r++) acc8(a2, L[r]);
#pragma unroll
        for (int r = 0; r < 4; r++) {
            int idx = 8 + 2 * r + el;
            int s = __shfl(sl2, qb + idx);
            int a = (idx < m2) ? s : n;
            L[r] = *(const float4*)(hs + (size_t)a * 64 + fl * 8);
        }
#pragma unroll
        for (int r = 0; r < 4; r++) acc8(a2, L[r]);
    }
    if (deg > 32) {
        for (int b0 = 32; b0 < deg; b0 += 16) {
            int mc = min(16, deg - b0);
            int sl3 = (ln < mc) ? col[beg + b0 + ln] : 0;
            for (int r = 0; r < 8; r++) {
                int idx = 2 * r + el;
                int s = __shfl(sl3, qb + idx);
                int a = (idx < mc) ? s : n;
                float4 v = *(const float4*)(hs + (size_t)a * 64 + fl * 8);
                acc8(a2, v);
            }
        }
    }
    float r[8];
#pragma unroll
    for (int j = 0; j < 4; j++) {
        float2 f = __half22float2(a2[j]);
        r[2 * j] = f.x;
        r[2 * j + 1] = f.y;
    }
#pragma unroll
    for (int j = 0; j < 8; j++) r[j] += __shfl_xor(r[j], 8);
    if (el == 0) {
        float d = dinv[w];
        float4 bb0 = *(const float4*)(b1 + fl * 8);
        float4 bb1 = *(const float4*)(b1 + fl * 8 + 4);
        union { float4 f; __half2 h[4]; } u;
        u.h[0] = __floats2half2_rn(fmaxf(r[0] * d + bb0.x, 0.f),
                                   fmaxf(r[1] * d + bb0.y, 0.f));
        u.h[1] = __floats2half2_rn(fmaxf(r[2] * d + bb0.z, 0.f),
                                   fmaxf(r[3] * d + bb0.w, 0.f));
        u.h[2] = __floats2half2_rn(fmaxf(r[4] * d + bb1.x, 0.f),
                                   fmaxf(r[5] * d + bb1.y, 0.f));
        u.h[3] = __floats2half2_rn(fmaxf(r[6] * d + bb1.z, 0.f),
                                   fmaxf(r[7] * d + bb1.w, 0.f));
        *(float4*)(h2 + (size_t)w * 64 + fl * 8) = u.f;
    }
}

__global__ __launch_bounds__(256) void k_mm2(const __half* __restrict__ h2,
                                             const float* __restrict__ W2,
                                             const float* __restrict__ dinv,
                                             __half* __restrict__ zs, int n) {
    __shared__ _Float16 Wt[32 * 72];
    int tid = threadIdx.x;
    int nbase = blockIdx.x * 64;
#pragma unroll
    for (int i = 0; i < 4; i++) {
        int f = tid + i * 256;
        int c = f & 31, kp = f >> 5;
        float a = W2[(size_t)(2 * kp) * 32 + c];
        float b = W2[(size_t)(2 * kp + 1) * 32 + c];
        *(__half2*)&Wt[c * 72 + 2 * kp] = __floats2half2_rn(a, b);
    }
    __syncthreads();
    int w = tid >> 6, lane = tid & 63;
    int quad = lane >> 4, m = lane & 15;
    int arow = nbase + w * 16 + m;
    const __half* abase = h2 + (size_t)min(arow, n - 1) * 64;
    floatx4 acc[2] = {{0.f, 0.f, 0.f, 0.f}, {0.f, 0.f, 0.f, 0.f}};
#pragma unroll
    for (int kt = 0; kt < 2; kt++) {
        half8 a = *(const half8*)(abase + kt * 32 + quad * 8);
#pragma unroll
        for (int ct = 0; ct < 2; ct++) {
            half8 b = *(const half8*)&Wt[(ct * 16 + m) * 72 + kt * 32 + quad * 8];
            acc[ct] = __builtin_amdgcn_mfma_f32_16x16x32_f16(a, b, acc[ct], 0, 0, 0);
        }
    }
#pragma unroll
    for (int reg = 0; reg < 4; reg++) {
        int node = nbase + w * 16 + quad * 4 + reg;
        if (node < n) {
            float d = dinv[node];
#pragma unroll
            for (int ct = 0; ct < 2; ct++) {
                zs[(size_t)node * 32 + ct * 16 + m] = __float2half(acc[ct][reg] * d);
            }
        }
    }
}

__global__ __launch_bounds__(256) void k_conv2(const __half* __restrict__ zs,
                                               const int* __restrict__ rowbeg,
                                               const int* __restrict__ rowend,
                                               const int* __restrict__ col,
                                               const float* __restrict__ dinv,
                                               const float* __restrict__ b2,
                                               float* __restrict__ zout,
                                               unsigned short* __restrict__ zh, int n) {
    int gw = (blockIdx.x * 256 + threadIdx.x) >> 6;
    int lane = threadIdx.x & 63;
    int q = lane >> 4, ln = lane & 15;
    int w = gw * 4 + q;
    if (w >= n) return;
    int qb = q << 4;
    int el = ln >> 2, fl = ln & 3;
    int beg = rowbeg[w], end = rowend[w];
    int deg = end - beg;
    int m = min(16, deg);
    int m2 = min(16, deg - 16);
    int sl = (ln < m) ? col[beg + ln] : 0;
    int sl2 = (ln < m2) ? col[beg + 16 + ln] : 0;
    __half2 a2[4];
#pragma unroll
    for (int j = 0; j < 4; j++) a2[j] = __half2half2(__float2half(0.f));
    int rs = (el == 0) ? w : n;
    float4 S = *(const float4*)(zs + (size_t)rs * 32 + fl * 8);
    float4 L[4];
#pragma unroll
    for (int r = 0; r < 4; r++) {
        int idx = 4 * r + el;
        int s = __shfl(sl, qb + idx);
        int a = (idx < m) ? s : n;
        L[r] = *(const float4*)(zs + (size_t)a * 32 + fl * 8);
    }
    acc8(a2, S);
#pragma unroll
    for (int r = 0; r < 4; r++) acc8(a2, L[r]);
    if (deg > 16) {
#pragma unroll
        for (int r = 0; r < 4; r++) {
            int idx = 4 * r + el;
            int s = __shfl(sl2, qb + idx);
            int a = (idx < m2) ? s : n;
            L[r] = *(const float4*)(zs + (size_t)a * 32 + fl * 8);
        }
#pragma unroll
        for (int r = 0; r < 4; r++) acc8(a2, L[r]);
    }
    if (deg > 32) {
        for (int b0 = 32; b0 < deg; b0 += 16) {
            int mc = min(16, deg - b0);
            int sl3 = (ln < mc) ? col[beg + b0 + ln] : 0;
            for (int r = 0; r < 4; r++) {
                int idx = 4 * r + el;
                int s = __shfl(sl3, qb + idx);
                int a = (idx < mc) ? s : n;
                float4 v = *(const float4*)(zs + (size_t)a * 32 + fl * 8);
                acc8(a2, v);
            }
        }
    }
    float r[8];
#pragma unroll
    for (int j = 0; j < 4; j++) {
        float2 f = __half22float2(a2[j]);
        r[2 * j] = f.x;
        r[2 * j + 1] = f.y;
    }
#pragma unroll
    for (int d = 4; d < 16; d <<= 1)
#pragma unroll
        for (int j = 0; j < 8; j++) r[j] += __shfl_xor(r[j], d);
    if (el == 0) {
        float d = dinv[w];
        float4 bb0 = *(const float4*)(b2 + fl * 8);
        float4 bb1 = *(const float4*)(b2 + fl * 8 + 4);
        float o0 = r[0] * d + bb0.x, o1 = r[1] * d + bb0.y;
        float o2 = r[2] * d + bb0.z, o3 = r[3] * d + bb0.w;
        float o4 = r[4] * d + bb1.x, o5 = r[5] * d + bb1.y;
        float o6 = r[6] * d + bb1.z, o7 = r[7] * d + bb1.w;
        *(float4*)(zout + (size_t)w * 32 + fl * 8) = make_float4(o0, o1, o2, o3);
        *(float4*)(zout + (size_t)w * 32 + fl * 8 + 4) = make_float4(o4, o5, o6, o7);
        uint4 p;
        p.x = (unsigned)f2bf(o0) | ((unsigned)f2bf(o1) << 16);
        p.y = (unsigned)f2bf(o2) | ((unsigned)f2bf(o3) << 16);
        p.z = (unsigned)f2bf(o4) | ((unsigned)f2bf(o5) << 16);
        p.w = (unsigned)f2bf(o6) | ((unsigned)f2bf(o7) << 16);
        *(uint4*)(zh + (size_t)w * 32 + fl * 8) = p;
    }
}

__global__ __launch_bounds__(256) void k_decode(const unsigned short* __restrict__ zh,
                                                const int* __restrict__ src,
                                                const int* __restrict__ tgt,
                                                float* __restrict__ recon, int E) {
    int g = (blockIdx.x * 256 + threadIdx.x) >> 2;
    int fl = threadIdx.x & 3;
    int e0 = g * 4;
    if (e0 >= E) return;
    int cnt = min(4, E - e0);
    int s[4], t[4];
#pragma unroll
    for (int q = 0; q < 4; q++) {
        int e = (q < cnt) ? e0 + q : e0;
        s[q] = src[e];
        t[q] = tgt[e];
    }
    uint4 Za[4], Zb[4];
#pragma unroll
    for (int q = 0; q < 4; q++) {
        Za[q] = *(const uint4*)(zh + (size_t)s[q] * 32 + fl * 8);
        Zb[q] = *(const uint4*)(zh + (size_t)t[q] * 32 + fl * 8);
    }
    float v[4];
#pragma unroll
    for (int q = 0; q < 4; q++) {
        float x = bfdot8(Za[q], Zb[q]);
        x += __shfl_xor(x, 1);
        x += __shfl_xor(x, 2);
        v[q] = x;
    }
    if (fl == 0) {
        if (cnt == 4) {
            *(float4*)(recon + e0) = make_float4(v[0], v[1], v[2], v[3]);
        } else {
            for (int q = 0; q < cnt; q++) recon[e0 + q] = v[q];
        }
    }
}

// ================================ host ======================================

extern "C" void kernel_launch(void* const* d_in, const int* in_sizes, int n_in,
                              void* d_out, int out_size, void* d_ws, size_t ws_size,
                              hipStream_t stream) {
    const float* x = (const float*)d_in[0];
    const float* W1 = (const float*)d_in[1];
    const float* b1 = (const float*)d_in[2];
    const float* W2 = (const float*)d_in[3];
    const float* b2 = (const float*)d_in[4];
    const int* ei = (const int*)d_in[5];

    int N = in_sizes[0] / 128;
    int E = in_sizes[5] / 2;
    const int* src = ei;
    const int* tgt = ei + E;
    int NB = divup(N, BNODES);

    char* ws = (char*)d_ws;
    size_t off = 0;
    auto alloc = [&](size_t bytes) {
        size_t r = off;
        off += (bytes + 255) & ~(size_t)255;
        return r;
    };
    int* gcur = (int*)(ws + alloc(NBMAX * 4));
    unsigned* ebuf = (unsigned*)(ws + alloc((size_t)NB * CAP * 4));
    int* col = (int*)(ws + alloc((size_t)NB * CAP * 4));
    int* rowbeg = (int*)(ws + alloc((size_t)N * 4));
    int* rowend = (int*)(ws + alloc((size_t)N * 4));
    float* dinv = (float*)(ws + alloc((size_t)N * 4));
    __half* hs = (__half*)(ws + alloc((size_t)(N + 1) * 64 * 2));   // +pad row n
    __half* h2 = (__half*)(ws + alloc((size_t)N * 64 * 2));
    __half* zs = (__half*)(ws + alloc((size_t)(N + 1) * 32 * 2));   // +pad row n
    unsigned short* zh = (unsigned short*)(ws + alloc((size_t)N * 32 * 2));

    float* zout = (float*)d_out;
    float* recon = zout + (size_t)N * 32;

    // grid size for cooperative launch: guaranteed co-resident.
    static int s_grid = 0;
    if (s_grid == 0) {
        hipDeviceProp_t prop;
        if (hipGetDeviceProperties(&prop, 0) != hipSuccess) prop.multiProcessorCount = 256;
        int m = 0;
        if (hipOccupancyMaxActiveBlocksPerMultiprocessor(&m, k_fused, 256, 0) != hipSuccess || m < 1)
            m = 1;
        long g = (long)m * (long)prop.multiProcessorCount;
        if (g > 2048) g = 2048;
        if (g < 1) g = 1;
        s_grid = (int)g;
    }

    GP p;
    p.x = x; p.W1 = W1; p.b1 = b1; p.W2 = W2; p.b2 = b2;
    p.src = src; p.tgt = tgt;
    p.gcur = gcur; p.ebuf = ebuf; p.col = col;
    p.rowbeg = rowbeg; p.rowend = rowend; p.dinv = dinv;
    p.hs = hs; p.h2 = h2; p.zs = zs; p.zh = zh;
    p.zout = zout; p.recon = recon;
    p.n = N; p.e = E; p.nb = NB; p.npart = divup(E, CHF);

    void* args[] = {(void*)&p};
    hipError_t err = hipLaunchCooperativeKernel((const void*)k_fused, dim3(s_grid),
                                                dim3(256), args, 0, stream);
    if (err != hipSuccess) {
        // fallback: legacy 8-dispatch pipeline (identical math)
        k_init<<<1, 256, 0, stream>>>(gcur, (unsigned*)(hs + (size_t)N * 64),
                                      (unsigned*)(zs + (size_t)N * 32));
        k_part<<<divup(E, CHF), 512, 0, stream>>>(src, tgt, gcur, ebuf, E, NB);
        k_bfill<<<NB, BNODES, 0, stream>>>(ebuf, gcur, rowbeg, rowend, col, dinv, N);
        k_mm1<<<divup(N, 128), 512, 0, stream>>>(x, W1, dinv, hs, N);
        k_conv1<<<divup(N, 16), 256, 0, stream>>>(hs, rowbeg, rowend, col, dinv, b1, h2, N);
        k_mm2<<<divup(N, 64), 256, 0, stream>>>(h2, W2, dinv, zs, N);
        k_conv2<<<divup(N, 16), 256, 0, stream>>>(zs, rowbeg, rowend, col, dinv, b2, zout, zh, N);
        k_decode<<<divup(E, 256), 256, 0, stream>>>(zh, src, tgt, recon, E);
    }
}

// Round 8
// 231.200 us; speedup vs baseline: 2.8663x; 2.8663x over previous
//
#include <hip/hip_runtime.h>
#include <hip/hip_fp16.h>
#include <math.h>

// GAE: 2x GCNConv + edge dot decode.
// R1-R10: bucketed CSR build, fp16 tables, wide gathers, MFMA mms,
//         4 nodes/wave gather convs.  (best: 228.2us)
// R11 FAILED: LDS decode latency-bound. R12/R14 NEUTRAL: build reshapes.
// R13/R15 MEASUREMENT: warm kernel ledger ~110us of the 226 total; additions
//      show 1:1 but reductions don't -> ~13us fixed cost per dispatch.
// R16 (226.2us, current best): mm1 A-fragments direct global->reg.
// R17 BIG FAIL (662us): cooperative mega-kernel; grid.sync ~100us each on
//      8-XCD MI355X (L2 flush across XCDs + 2048-block spin). Reverted.
// R18: dispatch-count reduction WITHOUT grid sync -- fuse mm1 INTO bfill.
//      bfill block b owns bucket b's 256 nodes and their dinv (s_cnt in
//      LDS); mm1 for those nodes depends on nothing else. Same MFMA order,
//      same conversions -> bit-identical hs. 8 -> 7 dispatches.

#define NBMAX 512    // max buckets (supports N <= 131072 at 256/bucket)
#define BSHIFT 8     // 256 nodes per bucket
#define BNODES 256
#define CHF 16384    // edges per partition block (98 at E=1.6M)
#define CAPSHIFT 13  // 8192 edge slots per bucket
#define CAP (1 << CAPSHIFT)

typedef _Float16 half8 __attribute__((ext_vector_type(8)));
typedef float floatx4 __attribute__((ext_vector_type(4)));

static inline int divup(int a, int b) { return (a + b - 1) / b; }

__device__ inline void acc8(__half2* a, float4 v) {
    const __half2* h = (const __half2*)&v;
    a[0] = __hadd2(a[0], h[0]);
    a[1] = __hadd2(a[1], h[1]);
    a[2] = __hadd2(a[2], h[2]);
    a[3] = __hadd2(a[3], h[3]);
}
__device__ inline unsigned short f2bf(float f) {
    unsigned u = __builtin_bit_cast(unsigned, f);
    u = (u + 0x7FFFu + ((u >> 16) & 1u)) >> 16;
    return (unsigned short)u;
}

// ---- init bucket cursors + zero pad rows ------------------------------------

__global__ void k_init(int* __restrict__ gcur, unsigned* __restrict__ hs_pad,
                       unsigned* __restrict__ zs_pad) {
    int t = threadIdx.x;
    for (int b = t; b < NBMAX; b += 256) gcur[b] = b << CAPSHIFT;
    if (t < 32) hs_pad[t] = 0;            // 128B zero row (64 fp16)
    else if (t < 48) zs_pad[t - 32] = 0;  // 64B zero row (32 fp16)
}

// ---- partition edges into fixed-capacity buckets (two-pass) -----------------
// ebuf word: (local_tgt << 23) | src   (src < 2^23, local_tgt < 256)

__global__ __launch_bounds__(512) void k_part(const int* __restrict__ src,
                                              const int* __restrict__ tgt,
                                              int* __restrict__ gcur,
                                              unsigned* __restrict__ ebuf, int E, int NB) {
    __shared__ int h[NBMAX];
    __shared__ int base[NBMAX];
    int tid = threadIdx.x;
    int e0 = blockIdx.x * CHF;
    for (int b = tid; b < NB; b += 512) h[b] = 0;
    __syncthreads();
#pragma unroll
    for (int r = 0; r < 8; r++) {
        int e = e0 + (r * 512 + tid) * 4;
        if (e + 3 < E) {
            int4 t4 = *(const int4*)(tgt + e);
            atomicAdd(&h[t4.x >> BSHIFT], 1);
            atomicAdd(&h[t4.y >> BSHIFT], 1);
            atomicAdd(&h[t4.z >> BSHIFT], 1);
            atomicAdd(&h[t4.w >> BSHIFT], 1);
        } else {
            for (int j = 0; j < 4; j++) {
                int ee = e + j;
                if (ee < E) atomicAdd(&h[tgt[ee] >> BSHIFT], 1);
            }
        }
    }
    __syncthreads();
    for (int b = tid; b < NB; b += 512) {
        int c = h[b];
        base[b] = c ? atomicAdd(&gcur[b], c) : 0;
    }
    __syncthreads();
#pragma unroll
    for (int r = 0; r < 8; r++) {
        int e = e0 + (r * 512 + tid) * 4;
        if (e + 3 < E) {
            int4 t4 = *(const int4*)(tgt + e);
            int4 s4 = *(const int4*)(src + e);
            int tv[4] = {t4.x, t4.y, t4.z, t4.w};
            int sw[4] = {s4.x, s4.y, s4.z, s4.w};
#pragma unroll
            for (int j = 0; j < 4; j++) {
                int t = tv[j];
                int pos = atomicAdd(&base[t >> BSHIFT], 1);
                ebuf[pos] = ((unsigned)(t & (BNODES - 1)) << 23) | (unsigned)sw[j];
            }
        } else {
            for (int j = 0; j < 4; j++) {
                int ee = e + j;
                if (ee < E) {
                    int t = tgt[ee];
                    int pos = atomicAdd(&base[t >> BSHIFT], 1);
                    ebuf[pos] = ((unsigned)(t & (BNODES - 1)) << 23) | (unsigned)src[ee];
                }
            }
        }
    }
}

// ---- bfill + mm1 fused ------------------------------------------------------
// Phase A (bfill): per-bucket count/scan/CSR-scatter + rowbeg/rowend/dinv.
// Phase B (mm1): block b computes hs rows for ITS 256 nodes -- dinv comes
// from the resident s_cnt, so the dependency is block-local (no grid sync).
// mm1 form = R16: A-fragment direct global->reg, Wt1 (fp16 W1^T) in LDS.

__global__ __launch_bounds__(256) void k_bfill_mm1(const unsigned* __restrict__ ebuf,
                                                   const int* __restrict__ gcur,
                                                   int* __restrict__ rowbeg,
                                                   int* __restrict__ rowend,
                                                   int* __restrict__ col,
                                                   float* __restrict__ dinv,
                                                   const float* __restrict__ x,
                                                   const float* __restrict__ W1,
                                                   __half* __restrict__ hs, int n) {
    __shared__ int s_cnt[BNODES];
    __shared__ int s_scan[BNODES];
    __shared__ int s_cur[BNODES];
    __shared__ _Float16 Wt[64 * 136];  // [col][k] (transposed W1, fp16)
    int b = blockIdx.x, tid = threadIdx.x;
    int nbase = b << BSHIFT;
    int ebase = b << CAPSHIFT;
    int eend = gcur[b];

    // stage Wt1 early (independent; hides under the count phase's latency)
#pragma unroll
    for (int i = 0; i < 16; i++) {
        int f = tid + i * 256;          // 0..4095
        int c = f & 63, kp = f >> 6;    // kp 0..63 (pairs of k)
        float a = W1[(size_t)(2 * kp) * 64 + c];
        float bb = W1[(size_t)(2 * kp + 1) * 64 + c];
        *(__half2*)&Wt[c * 136 + 2 * kp] = __floats2half2_rn(a, bb);
    }

    // --- phase A: bfill ---
    s_cnt[tid] = 0;
    __syncthreads();
    for (int e = ebase + tid; e < eend; e += BNODES) {
        atomicAdd(&s_cnt[ebuf[e] >> 23], 1);
    }
    __syncthreads();
    s_scan[tid] = s_cnt[tid];
    __syncthreads();
    for (int off = 1; off < BNODES; off <<= 1) {
        int t = (tid >= off) ? s_scan[tid - off] : 0;
        __syncthreads();
        s_scan[tid] += t;
        __syncthreads();
    }
    int excl = s_scan[tid] - s_cnt[tid];
    s_cur[tid] = excl;
    int node = nbase + tid;
    if (node < n) {
        rowbeg[node] = ebase + excl;
        rowend[node] = ebase + excl + s_cnt[tid];
        dinv[node] = rsqrtf((float)(s_cnt[tid] + 1));  // +1 self-loop
    }
    __syncthreads();
    for (int e = ebase + tid; e < eend; e += BNODES) {
        unsigned p = ebuf[e];
        int pos = atomicAdd(&s_cur[p >> 23], 1);
        col[ebase + pos] = (int)(p & 0x7FFFFFu);
    }
    __syncthreads();  // Wt + s_cnt stable for phase B

    // --- phase B: mm1 for this bucket's 256 nodes (4 passes x 64 rows) ---
    int w = tid >> 6, lane = tid & 63;
    int quad = lane >> 4, m = lane & 15;
#pragma unroll 1
    for (int pass = 0; pass < 4; pass++) {
        int lbase = pass * 64 + w * 16;
        int arow = nbase + lbase + m;
        const float* xb = x + (size_t)min(arow, n - 1) * 128;  // clamped row
        floatx4 acc[4] = {{0.f, 0.f, 0.f, 0.f}, {0.f, 0.f, 0.f, 0.f},
                          {0.f, 0.f, 0.f, 0.f}, {0.f, 0.f, 0.f, 0.f}};
#pragma unroll
        for (int kt = 0; kt < 4; kt++) {
            float4 v0 = *(const float4*)(xb + kt * 32 + quad * 8);
            float4 v1 = *(const float4*)(xb + kt * 32 + quad * 8 + 4);
            union { half8 h8; __half2 h2[4]; } ua;
            ua.h2[0] = __floats2half2_rn(v0.x, v0.y);
            ua.h2[1] = __floats2half2_rn(v0.z, v0.w);
            ua.h2[2] = __floats2half2_rn(v1.x, v1.y);
            ua.h2[3] = __floats2half2_rn(v1.z, v1.w);
#pragma unroll
            for (int ct = 0; ct < 4; ct++) {
                half8 bb = *(const half8*)&Wt[(ct * 16 + m) * 136 + kt * 32 + quad * 8];
                acc[ct] = __builtin_amdgcn_mfma_f32_16x16x32_f16(ua.h8, bb, acc[ct], 0, 0, 0);
            }
        }
#pragma unroll
        for (int reg = 0; reg < 4; reg++) {
            int lidx = lbase + quad * 4 + reg;
            int nd = nbase + lidx;
            if (nd < n) {
                float d = rsqrtf((float)(s_cnt[lidx] + 1));  // == dinv[nd]
#pragma unroll
                for (int ct = 0; ct < 4; ct++) {
                    hs[(size_t)nd * 64 + ct * 16 + m] = __float2half(acc[ct][reg] * d);
                }
            }
        }
    }
}

// ---- conv1: 4 nodes/wave (16-lane quarters), 8 feat lanes x 2 edge slots ----
// hs has a zeroed pad row at index n; invalid slots load it unconditionally.

__global__ __launch_bounds__(256) void k_conv1(const __half* __restrict__ hs,
                                               const int* __restrict__ rowbeg,
                                               const int* __restrict__ rowend,
                                               const int* __restrict__ col,
                                               const float* __restrict__ dinv,
                                               const float* __restrict__ b1,
                                               __half* __restrict__ h2, int n) {
    int gw = (blockIdx.x * 256 + threadIdx.x) >> 6;
    int lane = threadIdx.x & 63;
    int q = lane >> 4, ln = lane & 15;
    int w = gw * 4 + q;
    if (w >= n) return;  // whole quarter exits together
    int qb = q << 4;
    int el = ln >> 3, fl = ln & 7;  // 2 edge slots x 8 feat lanes
    int beg = rowbeg[w], end = rowend[w];
    int deg = end - beg;
    int m = min(16, deg);
    int m2 = min(16, deg - 16);  // may be <=0
    int sl = (ln < m) ? col[beg + ln] : 0;
    int sl2 = (ln < m2) ? col[beg + 16 + ln] : 0;
    __half2 a2[4];
#pragma unroll
    for (int j = 0; j < 4; j++) a2[j] = __half2half2(__float2half(0.f));
    // self + rounds 0..3 (edges 0..7)
    int rs = (el == 0) ? w : n;
    float4 S = *(const float4*)(hs + (size_t)rs * 64 + fl * 8);
    float4 L[4];
#pragma unroll
    for (int r = 0; r < 4; r++) {
        int idx = 2 * r + el;
        int s = __shfl(sl, qb + idx);
        int a = (idx < m) ? s : n;
        L[r] = *(const float4*)(hs + (size_t)a * 64 + fl * 8);
    }
    acc8(a2, S);
#pragma unroll
    for (int r = 0; r < 4; r++) acc8(a2, L[r]);
    // rounds 4..7 (edges 8..15)
#pragma unroll
    for (int r = 0; r < 4; r++) {
        int idx = 8 + 2 * r + el;
        int s = __shfl(sl, qb + idx);
        int a = (idx < m) ? s : n;
        L[r] = *(const float4*)(hs + (size_t)a * 64 + fl * 8);
    }
#pragma unroll
    for (int r = 0; r < 4; r++) acc8(a2, L[r]);
    if (deg > 16) {  // edges 16..31 from sl2 (~43% of nodes)
#pragma unroll
        for (int r = 0; r < 4; r++) {
            int idx = 2 * r + el;
            int s = __shfl(sl2, qb + idx);
            int a = (idx < m2) ? s : n;
            L[r] = *(const float4*)(hs + (size_t)a * 64 + fl * 8);
        }
#pragma unroll
        for (int r = 0; r < 4; r++) acc8(a2, L[r]);
#pragma unroll
        for (int r = 0; r < 4; r++) {
            int idx = 8 + 2 * r + el;
            int s = __shfl(sl2, qb + idx);
            int a = (idx < m2) ? s : n;
            L[r] = *(const float4*)(hs + (size_t)a * 64 + fl * 8);
        }
#pragma unroll
        for (int r = 0; r < 4; r++) acc8(a2, L[r]);
    }
    if (deg > 32) {  // rare (~0.01%)
        for (int b0 = 32; b0 < deg; b0 += 16) {
            int mc = min(16, deg - b0);
            int sl3 = (ln < mc) ? col[beg + b0 + ln] : 0;
            for (int r = 0; r < 8; r++) {
                int idx = 2 * r + el;
                int s = __shfl(sl3, qb + idx);
                int a = (idx < mc) ? s : n;
                float4 v = *(const float4*)(hs + (size_t)a * 64 + fl * 8);
                acc8(a2, v);
            }
        }
    }
    // fp32 reduction over the 2 el groups (d=8, intra-quarter)
    float r[8];
#pragma unroll
    for (int j = 0; j < 4; j++) {
        float2 f = __half22float2(a2[j]);
        r[2 * j] = f.x;
        r[2 * j + 1] = f.y;
    }
#pragma unroll
    for (int j = 0; j < 8; j++) r[j] += __shfl_xor(r[j], 8);

    if (el == 0) {
        float d = dinv[w];
        float4 bb0 = *(const float4*)(b1 + fl * 8);
        float4 bb1 = *(const float4*)(b1 + fl * 8 + 4);
        union { float4 f; __half2 h[4]; } u;
        u.h[0] = __floats2half2_rn(fmaxf(r[0] * d + bb0.x, 0.f),
                                   fmaxf(r[1] * d + bb0.y, 0.f));
        u.h[1] = __floats2half2_rn(fmaxf(r[2] * d + bb0.z, 0.f),
                                   fmaxf(r[3] * d + bb0.w, 0.f));
        u.h[2] = __floats2half2_rn(fmaxf(r[4] * d + bb1.x, 0.f),
                                   fmaxf(r[5] * d + bb1.y, 0.f));
        u.h[3] = __floats2half2_rn(fmaxf(r[6] * d + bb1.z, 0.f),
                                   fmaxf(r[7] * d + bb1.w, 0.f));
        *(float4*)(h2 + (size_t)w * 64 + fl * 8) = u.f;
    }
}

// ---- matmul 2 (MFMA): zs[n][c] = fp16((h2[n] @ W2[:,c]) * dinv[n]) ----------

__global__ __launch_bounds__(256) void k_mm2(const __half* __restrict__ h2,
                                             const float* __restrict__ W2,
                                             const float* __restrict__ dinv,
                                             __half* __restrict__ zs, int n) {
    __shared__ _Float16 Wt[32 * 72];  // [col][k] (transposed)
    int tid = threadIdx.x;
    int nbase = blockIdx.x * 64;
#pragma unroll
    for (int i = 0; i < 4; i++) {
        int f = tid + i * 256;          // 0..1023
        int c = f & 31, kp = f >> 5;    // kp 0..31
        float a = W2[(size_t)(2 * kp) * 32 + c];
        float b = W2[(size_t)(2 * kp + 1) * 32 + c];
        *(__half2*)&Wt[c * 72 + 2 * kp] = __floats2half2_rn(a, b);
    }
    __syncthreads();
    int w = tid >> 6, lane = tid & 63;
    int quad = lane >> 4, m = lane & 15;
    int arow = nbase + w * 16 + m;
    const __half* abase = h2 + (size_t)min(arow, n - 1) * 64;  // clamped rows
    floatx4 acc[2] = {{0.f, 0.f, 0.f, 0.f}, {0.f, 0.f, 0.f, 0.f}};
#pragma unroll
    for (int kt = 0; kt < 2; kt++) {
        half8 a = *(const half8*)(abase + kt * 32 + quad * 8);
#pragma unroll
        for (int ct = 0; ct < 2; ct++) {
            half8 b = *(const half8*)&Wt[(ct * 16 + m) * 72 + kt * 32 + quad * 8];
            acc[ct] = __builtin_amdgcn_mfma_f32_16x16x32_f16(a, b, acc[ct], 0, 0, 0);
        }
    }
#pragma unroll
    for (int reg = 0; reg < 4; reg++) {
        int node = nbase + w * 16 + quad * 4 + reg;
        if (node < n) {
            float d = dinv[node];
#pragma unroll
            for (int ct = 0; ct < 2; ct++) {
                zs[(size_t)node * 32 + ct * 16 + m] = __float2half(acc[ct][reg] * d);
            }
        }
    }
}

// ---- conv2: 4 nodes/wave (16-lane quarters), 4 feat lanes x 4 edge slots ----
// zs has a zeroed pad row at index n. bf16 zh epilogue for decode.

__global__ __launch_bounds__(256) void k_conv2(const __half* __restrict__ zs,
                                               const int* __restrict__ rowbeg,
                                               const int* __restrict__ rowend,
                                               const int* __restrict__ col,
                                               const float* __restrict__ dinv,
                                               const float* __restrict__ b2,
                                               float* __restrict__ zout,
                                               unsigned short* __restrict__ zh, int n) {
    int gw = (blockIdx.x * 256 + threadIdx.x) >> 6;
    int lane = threadIdx.x & 63;
    int q = lane >> 4, ln = lane & 15;
    int w = gw * 4 + q;
    if (w >= n) return;
    int qb = q << 4;
    int el = ln >> 2, fl = ln & 3;  // 4 edge slots x 4 feat lanes
    int beg = rowbeg[w], end = rowend[w];
    int deg = end - beg;
    int m = min(16, deg);
    int m2 = min(16, deg - 16);
    int sl = (ln < m) ? col[beg + ln] : 0;
    int sl2 = (ln < m2) ? col[beg + 16 + ln] : 0;
    __half2 a2[4];
#pragma unroll
    for (int j = 0; j < 4; j++) a2[j] = __half2half2(__float2half(0.f));
    int rs = (el == 0) ? w : n;
    float4 S = *(const float4*)(zs + (size_t)rs * 32 + fl * 8);
    float4 L[4];
#pragma unroll
    for (int r = 0; r < 4; r++) {  // edges 0..15
        int idx = 4 * r + el;
        int s = __shfl(sl, qb + idx);
        int a = (idx < m) ? s : n;
        L[r] = *(const float4*)(zs + (size_t)a * 32 + fl * 8);
    }
    acc8(a2, S);
#pragma unroll
    for (int r = 0; r < 4; r++) acc8(a2, L[r]);
    if (deg > 16) {  // edges 16..31
#pragma unroll
        for (int r = 0; r < 4; r++) {
            int idx = 4 * r + el;
            int s = __shfl(sl2, qb + idx);
            int a = (idx < m2) ? s : n;
            L[r] = *(const float4*)(zs + (size_t)a * 32 + fl * 8);
        }
#pragma unroll
        for (int r = 0; r < 4; r++) acc8(a2, L[r]);
    }
    if (deg > 32) {  // rare
        for (int b0 = 32; b0 < deg; b0 += 16) {
            int mc = min(16, deg - b0);
            int sl3 = (ln < mc) ? col[beg + b0 + ln] : 0;
            for (int r = 0; r < 4; r++) {
                int idx = 4 * r + el;
                int s = __shfl(sl3, qb + idx);
                int a = (idx < mc) ? s : n;
                float4 v = *(const float4*)(zs + (size_t)a * 32 + fl * 8);
                acc8(a2, v);
            }
        }
    }
    // fp32 reduction over the 4 el groups (d=4,8 intra-quarter)
    float r[8];
#pragma unroll
    for (int j = 0; j < 4; j++) {
        float2 f = __half22float2(a2[j]);
        r[2 * j] = f.x;
        r[2 * j + 1] = f.y;
    }
#pragma unroll
    for (int d = 4; d < 16; d <<= 1)
#pragma unroll
        for (int j = 0; j < 8; j++) r[j] += __shfl_xor(r[j], d);

    if (el == 0) {  // lanes fl=0..3 of each quarter, 8 feats each
        float d = dinv[w];
        float4 bb0 = *(const float4*)(b2 + fl * 8);
        float4 bb1 = *(const float4*)(b2 + fl * 8 + 4);
        float o0 = r[0] * d + bb0.x, o1 = r[1] * d + bb0.y;
        float o2 = r[2] * d + bb0.z, o3 = r[3] * d + bb0.w;
        float o4 = r[4] * d + bb1.x, o5 = r[5] * d + bb1.y;
        float o6 = r[6] * d + bb1.z, o7 = r[7] * d + bb1.w;
        *(float4*)(zout + (size_t)w * 32 + fl * 8) = make_float4(o0, o1, o2, o3);
        *(float4*)(zout + (size_t)w * 32 + fl * 8 + 4) = make_float4(o4, o5, o6, o7);
        uint4 p;
        p.x = (unsigned)f2bf(o0) | ((unsigned)f2bf(o1) << 16);
        p.y = (unsigned)f2bf(o2) | ((unsigned)f2bf(o3) << 16);
        p.z = (unsigned)f2bf(o4) | ((unsigned)f2bf(o5) << 16);
        p.w = (unsigned)f2bf(o6) | ((unsigned)f2bf(o7) << 16);
        *(uint4*)(zh + (size_t)w * 32 + fl * 8) = p;
    }
}

// ---- decode: bf16 rows (64B), 4 lanes/edge, 4 edges per group ---------------
// zh is 6.4MB -> L2/L3-resident; 8 independent uint4 loads per group give the
// MLP that makes this latency-tolerant (R11 lesson: do not serialize).

__device__ inline float bfdot8(uint4 a, uint4 b) {
    const unsigned* pa = (const unsigned*)&a;
    const unsigned* pb = (const unsigned*)&b;
    float v = 0.f;
#pragma unroll
    for (int w = 0; w < 4; w++) {
        float alo = __builtin_bit_cast(float, pa[w] << 16);
        float ahi = __builtin_bit_cast(float, pa[w] & 0xFFFF0000u);
        float blo = __builtin_bit_cast(float, pb[w] << 16);
        float bhi = __builtin_bit_cast(float, pb[w] & 0xFFFF0000u);
        v += alo * blo + ahi * bhi;
    }
    return v;
}

__global__ __launch_bounds__(256) void k_decode(const unsigned short* __restrict__ zh,
                                                const int* __restrict__ src,
                                                const int* __restrict__ tgt,
                                                float* __restrict__ recon, int E) {
    int g = (blockIdx.x * 256 + threadIdx.x) >> 2;
    int fl = threadIdx.x & 3;
    int e0 = g * 4;
    if (e0 >= E) return;
    int cnt = min(4, E - e0);
    int s[4], t[4];
#pragma unroll
    for (int q = 0; q < 4; q++) {
        int e = (q < cnt) ? e0 + q : e0;
        s[q] = src[e];
        t[q] = tgt[e];
    }
    uint4 Za[4], Zb[4];
#pragma unroll
    for (int q = 0; q < 4; q++) {
        Za[q] = *(const uint4*)(zh + (size_t)s[q] * 32 + fl * 8);
        Zb[q] = *(const uint4*)(zh + (size_t)t[q] * 32 + fl * 8);
    }
    float v[4];
#pragma unroll
    for (int q = 0; q < 4; q++) {
        float x = bfdot8(Za[q], Zb[q]);
        x += __shfl_xor(x, 1);
        x += __shfl_xor(x, 2);
        v[q] = x;
    }
    if (fl == 0) {
        if (cnt == 4) {
            *(float4*)(recon + e0) = make_float4(v[0], v[1], v[2], v[3]);
        } else {
            for (int q = 0; q < cnt; q++) recon[e0 + q] = v[q];
        }
    }
}

extern "C" void kernel_launch(void* const* d_in, const int* in_sizes, int n_in,
                              void* d_out, int out_size, void* d_ws, size_t ws_size,
                              hipStream_t stream) {
    const float* x = (const float*)d_in[0];
    const float* W1 = (const float*)d_in[1];
    const float* b1 = (const float*)d_in[2];
    const float* W2 = (const float*)d_in[3];
    const float* b2 = (const float*)d_in[4];
    const int* ei = (const int*)d_in[5];

    int N = in_sizes[0] / 128;
    int E = in_sizes[5] / 2;
    const int* src = ei;
    const int* tgt = ei + E;
    int NB = divup(N, BNODES);

    char* ws = (char*)d_ws;
    size_t off = 0;
    auto alloc = [&](size_t bytes) {
        size_t r = off;
        off += (bytes + 255) & ~(size_t)255;
        return r;
    };
    int* gcur = (int*)(ws + alloc(NBMAX * 4));
    unsigned* ebuf = (unsigned*)(ws + alloc((size_t)NB * CAP * 4));
    int* col = (int*)(ws + alloc((size_t)NB * CAP * 4));
    int* rowbeg = (int*)(ws + alloc((size_t)N * 4));
    int* rowend = (int*)(ws + alloc((size_t)N * 4));
    float* dinv = (float*)(ws + alloc((size_t)N * 4));
    __half* hs = (__half*)(ws + alloc((size_t)(N + 1) * 64 * 2));   // +pad row n
    __half* h2 = (__half*)(ws + alloc((size_t)N * 64 * 2));
    __half* zs = (__half*)(ws + alloc((size_t)(N + 1) * 32 * 2));   // +pad row n
    unsigned short* zh = (unsigned short*)(ws + alloc((size_t)N * 32 * 2));

    float* zout = (float*)d_out;
    float* recon = zout + (size_t)N * 32;

    k_init<<<1, 256, 0, stream>>>(gcur, (unsigned*)(hs + (size_t)N * 64),
                                  (unsigned*)(zs + (size_t)N * 32));
    k_part<<<divup(E, CHF), 512, 0, stream>>>(src, tgt, gcur, ebuf, E, NB);
    k_bfill_mm1<<<NB, BNODES, 0, stream>>>(ebuf, gcur, rowbeg, rowend, col, dinv,
                                           x, W1, hs, N);
    k_conv1<<<divup(N, 16), 256, 0, stream>>>(hs, rowbeg, rowend, col, dinv, b1, h2, N);
    k_mm2<<<divup(N, 64), 256, 0, stream>>>(h2, W2, dinv, zs, N);
    k_conv2<<<divup(N, 16), 256, 0, stream>>>(zs, rowbeg, rowend, col, dinv, b2, zout, zh, N);
    k_decode<<<divup(E, 256), 256, 0, stream>>>(zh, src, tgt, recon, E);
}

// Round 9
// 223.366 us; speedup vs baseline: 2.9668x; 1.0351x over previous
//
#include <hip/hip_runtime.h>
#include <hip/hip_fp16.h>
#include <math.h>

// GAE: 2x GCNConv + edge dot decode.
// R1-R10: bucketed CSR build, fp16 tables, wide gathers, MFMA mms,
//         4 nodes/wave gather convs.  (best: 228.2us)
// R11 FAILED: LDS decode latency-bound. R12/R14 NEUTRAL: build reshapes.
// R13/R15 MEASUREMENT: warm kernel ledger ~110-125us of the ~226 total;
//      additions show 1:1; reductions partially absorbed by ~8us/dispatch
//      fixed cost + harness poison fills (~44us, uncontrollable).
// R16 (226.2us, prior best): mm1 A-fragments direct global->reg.
// R17 BIG FAIL (662us): cooperative grid.sync ~100us each on 8 XCDs.
// R18 REGRESSED (231.2us): bfill+mm1 fusion degraded mm1's geometry
//      (4 waves/block, 391 blocks, 20.5KB LDS) -- fusion must not change
//      the parts' launch geometry. Reverted.
// R19: fuse mm2 INTO conv1 instead: conv1 block = exactly 16 consecutive
//      nodes = one MFMA 16-row tile. h2 row goes to a pitch-72 LDS tile
//      (never to global); wave 0 then runs k_mm2's exact MFMA sequence
//      (same Wt2 staging, fragments, dinv) -> bit-identical zs. 8->7
//      dispatches AND -25.6MB h2 write+read traffic.

#define NBMAX 512    // max buckets (supports N <= 131072 at 256/bucket)
#define BSHIFT 8     // 256 nodes per bucket
#define BNODES 256
#define CHF 16384    // edges per partition block (98 at E=1.6M)
#define CAPSHIFT 13  // 8192 edge slots per bucket
#define CAP (1 << CAPSHIFT)

typedef _Float16 half8 __attribute__((ext_vector_type(8)));
typedef float floatx4 __attribute__((ext_vector_type(4)));

static inline int divup(int a, int b) { return (a + b - 1) / b; }

__device__ inline void acc8(__half2* a, float4 v) {
    const __half2* h = (const __half2*)&v;
    a[0] = __hadd2(a[0], h[0]);
    a[1] = __hadd2(a[1], h[1]);
    a[2] = __hadd2(a[2], h[2]);
    a[3] = __hadd2(a[3], h[3]);
}
__device__ inline unsigned short f2bf(float f) {
    unsigned u = __builtin_bit_cast(unsigned, f);
    u = (u + 0x7FFFu + ((u >> 16) & 1u)) >> 16;
    return (unsigned short)u;
}

// ---- init bucket cursors + zero pad rows ------------------------------------

__global__ void k_init(int* __restrict__ gcur, unsigned* __restrict__ hs_pad,
                       unsigned* __restrict__ zs_pad) {
    int t = threadIdx.x;
    for (int b = t; b < NBMAX; b += 256) gcur[b] = b << CAPSHIFT;
    if (t < 32) hs_pad[t] = 0;            // 128B zero row (64 fp16)
    else if (t < 48) zs_pad[t - 32] = 0;  // 64B zero row (32 fp16)
}

// ---- partition edges into fixed-capacity buckets (two-pass) -----------------
// ebuf word: (local_tgt << 23) | src   (src < 2^23, local_tgt < 256)

__global__ __launch_bounds__(512) void k_part(const int* __restrict__ src,
                                              const int* __restrict__ tgt,
                                              int* __restrict__ gcur,
                                              unsigned* __restrict__ ebuf, int E, int NB) {
    __shared__ int h[NBMAX];
    __shared__ int base[NBMAX];
    int tid = threadIdx.x;
    int e0 = blockIdx.x * CHF;
    for (int b = tid; b < NB; b += 512) h[b] = 0;
    __syncthreads();
#pragma unroll
    for (int r = 0; r < 8; r++) {
        int e = e0 + (r * 512 + tid) * 4;
        if (e + 3 < E) {
            int4 t4 = *(const int4*)(tgt + e);
            atomicAdd(&h[t4.x >> BSHIFT], 1);
            atomicAdd(&h[t4.y >> BSHIFT], 1);
            atomicAdd(&h[t4.z >> BSHIFT], 1);
            atomicAdd(&h[t4.w >> BSHIFT], 1);
        } else {
            for (int j = 0; j < 4; j++) {
                int ee = e + j;
                if (ee < E) atomicAdd(&h[tgt[ee] >> BSHIFT], 1);
            }
        }
    }
    __syncthreads();
    for (int b = tid; b < NB; b += 512) {
        int c = h[b];
        base[b] = c ? atomicAdd(&gcur[b], c) : 0;
    }
    __syncthreads();
#pragma unroll
    for (int r = 0; r < 8; r++) {
        int e = e0 + (r * 512 + tid) * 4;
        if (e + 3 < E) {
            int4 t4 = *(const int4*)(tgt + e);
            int4 s4 = *(const int4*)(src + e);
            int tv[4] = {t4.x, t4.y, t4.z, t4.w};
            int sw[4] = {s4.x, s4.y, s4.z, s4.w};
#pragma unroll
            for (int j = 0; j < 4; j++) {
                int t = tv[j];
                int pos = atomicAdd(&base[t >> BSHIFT], 1);
                ebuf[pos] = ((unsigned)(t & (BNODES - 1)) << 23) | (unsigned)sw[j];
            }
        } else {
            for (int j = 0; j < 4; j++) {
                int ee = e + j;
                if (ee < E) {
                    int t = tgt[ee];
                    int pos = atomicAdd(&base[t >> BSHIFT], 1);
                    ebuf[pos] = ((unsigned)(t & (BNODES - 1)) << 23) | (unsigned)src[ee];
                }
            }
        }
    }
}

// ---- per-bucket CSR fill: LDS count/scan/cursor -----------------------------

__global__ __launch_bounds__(256) void k_bfill(const unsigned* __restrict__ ebuf,
                                               const int* __restrict__ gcur,
                                               int* __restrict__ rowbeg,
                                               int* __restrict__ rowend,
                                               int* __restrict__ col,
                                               float* __restrict__ dinv, int n) {
    __shared__ int s_cnt[BNODES];
    __shared__ int s_scan[BNODES];
    __shared__ int s_cur[BNODES];
    int b = blockIdx.x, tid = threadIdx.x;
    int nbase = b << BSHIFT;
    int ebase = b << CAPSHIFT;
    int eend = gcur[b];
    s_cnt[tid] = 0;
    __syncthreads();
    for (int e = ebase + tid; e < eend; e += BNODES) {
        atomicAdd(&s_cnt[ebuf[e] >> 23], 1);
    }
    __syncthreads();
    s_scan[tid] = s_cnt[tid];
    __syncthreads();
    for (int off = 1; off < BNODES; off <<= 1) {
        int t = (tid >= off) ? s_scan[tid - off] : 0;
        __syncthreads();
        s_scan[tid] += t;
        __syncthreads();
    }
    int excl = s_scan[tid] - s_cnt[tid];
    s_cur[tid] = excl;
    int node = nbase + tid;
    if (node < n) {
        rowbeg[node] = ebase + excl;
        rowend[node] = ebase + excl + s_cnt[tid];
        dinv[node] = rsqrtf((float)(s_cnt[tid] + 1));  // +1 self-loop
    }
    __syncthreads();
    for (int e = ebase + tid; e < eend; e += BNODES) {
        unsigned p = ebuf[e];
        int pos = atomicAdd(&s_cur[p >> 23], 1);
        col[ebase + pos] = (int)(p & 0x7FFFFFu);
    }
}

// ---- matmul 1 (MFMA): hs[n][j] = fp16((x[n] @ W1[:,j]) * dinv[n]) -----------
// R16 form: A-fragments direct global->reg; Wt1 in LDS; 512 thr, 128 nodes.

__global__ __launch_bounds__(512) void k_mm1(const float* __restrict__ x,
                                             const float* __restrict__ W1,
                                             const float* __restrict__ dinv,
                                             __half* __restrict__ hs, int n) {
    __shared__ _Float16 Wt[64 * 136];  // [col][k] (transposed)
    int tid = threadIdx.x;
    int nbase = blockIdx.x * 128;
#pragma unroll
    for (int i = 0; i < 8; i++) {
        int f = tid + i * 512;          // 0..4095
        int c = f & 63, kp = f >> 6;    // kp 0..63 (pairs of k)
        float a = W1[(size_t)(2 * kp) * 64 + c];
        float b = W1[(size_t)(2 * kp + 1) * 64 + c];
        *(__half2*)&Wt[c * 136 + 2 * kp] = __floats2half2_rn(a, b);
    }
    __syncthreads();
    int w = tid >> 6, lane = tid & 63;
    int quad = lane >> 4, m = lane & 15;
    int arow = nbase + w * 16 + m;
    const float* xb = x + (size_t)min(arow, n - 1) * 128;  // clamped row
    floatx4 acc[4] = {{0.f, 0.f, 0.f, 0.f}, {0.f, 0.f, 0.f, 0.f},
                      {0.f, 0.f, 0.f, 0.f}, {0.f, 0.f, 0.f, 0.f}};
#pragma unroll
    for (int kt = 0; kt < 4; kt++) {
        float4 v0 = *(const float4*)(xb + kt * 32 + quad * 8);
        float4 v1 = *(const float4*)(xb + kt * 32 + quad * 8 + 4);
        union { half8 h8; __half2 h2[4]; } ua;
        ua.h2[0] = __floats2half2_rn(v0.x, v0.y);
        ua.h2[1] = __floats2half2_rn(v0.z, v0.w);
        ua.h2[2] = __floats2half2_rn(v1.x, v1.y);
        ua.h2[3] = __floats2half2_rn(v1.z, v1.w);
#pragma unroll
        for (int ct = 0; ct < 4; ct++) {
            half8 b = *(const half8*)&Wt[(ct * 16 + m) * 136 + kt * 32 + quad * 8];
            acc[ct] = __builtin_amdgcn_mfma_f32_16x16x32_f16(ua.h8, b, acc[ct], 0, 0, 0);
        }
    }
#pragma unroll
    for (int reg = 0; reg < 4; reg++) {
        int node = nbase + w * 16 + quad * 4 + reg;
        if (node < n) {
            float d = dinv[node];
#pragma unroll
            for (int ct = 0; ct < 4; ct++) {
                hs[(size_t)node * 64 + ct * 16 + m] = __float2half(acc[ct][reg] * d);
            }
        }
    }
}

// ---- conv1 + mm2 fused ------------------------------------------------------
// conv1: 4 nodes/wave (16-lane quarters), 8 feat lanes x 2 edge slots. The
// block's 16 nodes = one MFMA 16-row tile. h2 rows land in a pitch-72 LDS
// tile (never in global). Wave 0 then runs k_mm2's exact MFMA sequence
// (same Wt2 fp16 staging, same fragments, same dinv scale) -> zs identical.

__global__ __launch_bounds__(256) void k_conv1mm2(const __half* __restrict__ hs,
                                                  const int* __restrict__ rowbeg,
                                                  const int* __restrict__ rowend,
                                                  const int* __restrict__ col,
                                                  const float* __restrict__ dinv,
                                                  const float* __restrict__ b1,
                                                  const float* __restrict__ W2,
                                                  __half* __restrict__ zs, int n) {
    __shared__ _Float16 Wt[32 * 72];   // transposed W2, fp16 (as in k_mm2)
    __shared__ _Float16 h2s[16 * 72];  // block's 16 h2 rows, pitch 72 (bank-clean)
    int tid = threadIdx.x;
    // stage Wt2 (identical to k_mm2's staging)
#pragma unroll
    for (int i = 0; i < 4; i++) {
        int f = tid + i * 256;          // 0..1023
        int c = f & 31, kp = f >> 5;    // kp 0..31
        float a = W2[(size_t)(2 * kp) * 32 + c];
        float b = W2[(size_t)(2 * kp + 1) * 32 + c];
        *(__half2*)&Wt[c * 72 + 2 * kp] = __floats2half2_rn(a, b);
    }

    int gw = (blockIdx.x * 256 + tid) >> 6;
    int lane = tid & 63;
    int q = lane >> 4, ln = lane & 15;
    int w = gw * 4 + q;
    int qb = q << 4;
    int el = ln >> 3, fl = ln & 7;  // 2 edge slots x 8 feat lanes
    if (w < n) {
        int beg = rowbeg[w], end = rowend[w];
        int deg = end - beg;
        int m = min(16, deg);
        int m2 = min(16, deg - 16);  // may be <=0
        int sl = (ln < m) ? col[beg + ln] : 0;
        int sl2 = (ln < m2) ? col[beg + 16 + ln] : 0;
        __half2 a2[4];
#pragma unroll
        for (int j = 0; j < 4; j++) a2[j] = __half2half2(__float2half(0.f));
        // self + rounds 0..3 (edges 0..7)
        int rs = (el == 0) ? w : n;
        float4 S = *(const float4*)(hs + (size_t)rs * 64 + fl * 8);
        float4 L[4];
#pragma unroll
        for (int r = 0; r < 4; r++) {
            int idx = 2 * r + el;
            int s = __shfl(sl, qb + idx);
            int a = (idx < m) ? s : n;
            L[r] = *(const float4*)(hs + (size_t)a * 64 + fl * 8);
        }
        acc8(a2, S);
#pragma unroll
        for (int r = 0; r < 4; r++) acc8(a2, L[r]);
        // rounds 4..7 (edges 8..15)
#pragma unroll
        for (int r = 0; r < 4; r++) {
            int idx = 8 + 2 * r + el;
            int s = __shfl(sl, qb + idx);
            int a = (idx < m) ? s : n;
            L[r] = *(const float4*)(hs + (size_t)a * 64 + fl * 8);
        }
#pragma unroll
        for (int r = 0; r < 4; r++) acc8(a2, L[r]);
        if (deg > 16) {  // edges 16..31 from sl2 (~43% of nodes)
#pragma unroll
            for (int r = 0; r < 4; r++) {
                int idx = 2 * r + el;
                int s = __shfl(sl2, qb + idx);
                int a = (idx < m2) ? s : n;
                L[r] = *(const float4*)(hs + (size_t)a * 64 + fl * 8);
            }
#pragma unroll
            for (int r = 0; r < 4; r++) acc8(a2, L[r]);
#pragma unroll
            for (int r = 0; r < 4; r++) {
                int idx = 8 + 2 * r + el;
                int s = __shfl(sl2, qb + idx);
                int a = (idx < m2) ? s : n;
                L[r] = *(const float4*)(hs + (size_t)a * 64 + fl * 8);
            }
#pragma unroll
            for (int r = 0; r < 4; r++) acc8(a2, L[r]);
        }
        if (deg > 32) {  // rare (~0.01%)
            for (int b0 = 32; b0 < deg; b0 += 16) {
                int mc = min(16, deg - b0);
                int sl3 = (ln < mc) ? col[beg + b0 + ln] : 0;
                for (int r = 0; r < 8; r++) {
                    int idx = 2 * r + el;
                    int s = __shfl(sl3, qb + idx);
                    int a = (idx < mc) ? s : n;
                    float4 v = *(const float4*)(hs + (size_t)a * 64 + fl * 8);
                    acc8(a2, v);
                }
            }
        }
        // fp32 reduction over the 2 el groups (d=8, intra-quarter)
        float r[8];
#pragma unroll
        for (int j = 0; j < 4; j++) {
            float2 f = __half22float2(a2[j]);
            r[2 * j] = f.x;
            r[2 * j + 1] = f.y;
        }
#pragma unroll
        for (int j = 0; j < 8; j++) r[j] += __shfl_xor(r[j], 8);

        if (el == 0) {
            float d = dinv[w];
            float4 bb0 = *(const float4*)(b1 + fl * 8);
            float4 bb1 = *(const float4*)(b1 + fl * 8 + 4);
            union { float4 f; __half2 h[4]; } u;
            u.h[0] = __floats2half2_rn(fmaxf(r[0] * d + bb0.x, 0.f),
                                       fmaxf(r[1] * d + bb0.y, 0.f));
            u.h[1] = __floats2half2_rn(fmaxf(r[2] * d + bb0.z, 0.f),
                                       fmaxf(r[3] * d + bb0.w, 0.f));
            u.h[2] = __floats2half2_rn(fmaxf(r[4] * d + bb1.x, 0.f),
                                       fmaxf(r[5] * d + bb1.y, 0.f));
            u.h[3] = __floats2half2_rn(fmaxf(r[6] * d + bb1.z, 0.f),
                                       fmaxf(r[7] * d + bb1.w, 0.f));
            *(float4*)&h2s[(w & 15) * 72 + fl * 8] = u.f;  // block-local row
        }
    }
    __syncthreads();

    // mm2 phase: wave 0 computes zs for the block's 16 nodes (= 1 row tile).
    if (tid < 64) {
        int quad = tid >> 4, m = tid & 15;
        int nbase = blockIdx.x * 16;
        floatx4 acc[2] = {{0.f, 0.f, 0.f, 0.f}, {0.f, 0.f, 0.f, 0.f}};
#pragma unroll
        for (int kt = 0; kt < 2; kt++) {
            half8 a = *(const half8*)&h2s[m * 72 + kt * 32 + quad * 8];
#pragma unroll
            for (int ct = 0; ct < 2; ct++) {
                half8 b = *(const half8*)&Wt[(ct * 16 + m) * 72 + kt * 32 + quad * 8];
                acc[ct] = __builtin_amdgcn_mfma_f32_16x16x32_f16(a, b, acc[ct], 0, 0, 0);
            }
        }
#pragma unroll
        for (int reg = 0; reg < 4; reg++) {
            int node = nbase + quad * 4 + reg;
            if (node < n) {
                float d = dinv[node];
#pragma unroll
                for (int ct = 0; ct < 2; ct++) {
                    zs[(size_t)node * 32 + ct * 16 + m] = __float2half(acc[ct][reg] * d);
                }
            }
        }
    }
}

// ---- conv2: 4 nodes/wave (16-lane quarters), 4 feat lanes x 4 edge slots ----
// zs has a zeroed pad row at index n. bf16 zh epilogue for decode.

__global__ __launch_bounds__(256) void k_conv2(const __half* __restrict__ zs,
                                               const int* __restrict__ rowbeg,
                                               const int* __restrict__ rowend,
                                               const int* __restrict__ col,
                                               const float* __restrict__ dinv,
                                               const float* __restrict__ b2,
                                               float* __restrict__ zout,
                                               unsigned short* __restrict__ zh, int n) {
    int gw = (blockIdx.x * 256 + threadIdx.x) >> 6;
    int lane = threadIdx.x & 63;
    int q = lane >> 4, ln = lane & 15;
    int w = gw * 4 + q;
    if (w >= n) return;
    int qb = q << 4;
    int el = ln >> 2, fl = ln & 3;  // 4 edge slots x 4 feat lanes
    int beg = rowbeg[w], end = rowend[w];
    int deg = end - beg;
    int m = min(16, deg);
    int m2 = min(16, deg - 16);
    int sl = (ln < m) ? col[beg + ln] : 0;
    int sl2 = (ln < m2) ? col[beg + 16 + ln] : 0;
    __half2 a2[4];
#pragma unroll
    for (int j = 0; j < 4; j++) a2[j] = __half2half2(__float2half(0.f));
    int rs = (el == 0) ? w : n;
    float4 S = *(const float4*)(zs + (size_t)rs * 32 + fl * 8);
    float4 L[4];
#pragma unroll
    for (int r = 0; r < 4; r++) {  // edges 0..15
        int idx = 4 * r + el;
        int s = __shfl(sl, qb + idx);
        int a = (idx < m) ? s : n;
        L[r] = *(const float4*)(zs + (size_t)a * 32 + fl * 8);
    }
    acc8(a2, S);
#pragma unroll
    for (int r = 0; r < 4; r++) acc8(a2, L[r]);
    if (deg > 16) {  // edges 16..31
#pragma unroll
        for (int r = 0; r < 4; r++) {
            int idx = 4 * r + el;
            int s = __shfl(sl2, qb + idx);
            int a = (idx < m2) ? s : n;
            L[r] = *(const float4*)(zs + (size_t)a * 32 + fl * 8);
        }
#pragma unroll
        for (int r = 0; r < 4; r++) acc8(a2, L[r]);
    }
    if (deg > 32) {  // rare
        for (int b0 = 32; b0 < deg; b0 += 16) {
            int mc = min(16, deg - b0);
            int sl3 = (ln < mc) ? col[beg + b0 + ln] : 0;
            for (int r = 0; r < 4; r++) {
                int idx = 4 * r + el;
                int s = __shfl(sl3, qb + idx);
                int a = (idx < mc) ? s : n;
                float4 v = *(const float4*)(zs + (size_t)a * 32 + fl * 8);
                acc8(a2, v);
            }
        }
    }
    // fp32 reduction over the 4 el groups (d=4,8 intra-quarter)
    float r[8];
#pragma unroll
    for (int j = 0; j < 4; j++) {
        float2 f = __half22float2(a2[j]);
        r[2 * j] = f.x;
        r[2 * j + 1] = f.y;
    }
#pragma unroll
    for (int d = 4; d < 16; d <<= 1)
#pragma unroll
        for (int j = 0; j < 8; j++) r[j] += __shfl_xor(r[j], d);

    if (el == 0) {  // lanes fl=0..3 of each quarter, 8 feats each
        float d = dinv[w];
        float4 bb0 = *(const float4*)(b2 + fl * 8);
        float4 bb1 = *(const float4*)(b2 + fl * 8 + 4);
        float o0 = r[0] * d + bb0.x, o1 = r[1] * d + bb0.y;
        float o2 = r[2] * d + bb0.z, o3 = r[3] * d + bb0.w;
        float o4 = r[4] * d + bb1.x, o5 = r[5] * d + bb1.y;
        float o6 = r[6] * d + bb1.z, o7 = r[7] * d + bb1.w;
        *(float4*)(zout + (size_t)w * 32 + fl * 8) = make_float4(o0, o1, o2, o3);
        *(float4*)(zout + (size_t)w * 32 + fl * 8 + 4) = make_float4(o4, o5, o6, o7);
        uint4 p;
        p.x = (unsigned)f2bf(o0) | ((unsigned)f2bf(o1) << 16);
        p.y = (unsigned)f2bf(o2) | ((unsigned)f2bf(o3) << 16);
        p.z = (unsigned)f2bf(o4) | ((unsigned)f2bf(o5) << 16);
        p.w = (unsigned)f2bf(o6) | ((unsigned)f2bf(o7) << 16);
        *(uint4*)(zh + (size_t)w * 32 + fl * 8) = p;
    }
}

// ---- decode: bf16 rows (64B), 4 lanes/edge, 4 edges per group ---------------
// zh is 6.4MB -> L2/L3-resident; 8 independent uint4 loads per group give the
// MLP that makes this latency-tolerant (R11 lesson: do not serialize).

__device__ inline float bfdot8(uint4 a, uint4 b) {
    const unsigned* pa = (const unsigned*)&a;
    const unsigned* pb = (const unsigned*)&b;
    float v = 0.f;
#pragma unroll
    for (int w = 0; w < 4; w++) {
        float alo = __builtin_bit_cast(float, pa[w] << 16);
        float ahi = __builtin_bit_cast(float, pa[w] & 0xFFFF0000u);
        float blo = __builtin_bit_cast(float, pb[w] << 16);
        float bhi = __builtin_bit_cast(float, pb[w] & 0xFFFF0000u);
        v += alo * blo + ahi * bhi;
    }
    return v;
}

__global__ __launch_bounds__(256) void k_decode(const unsigned short* __restrict__ zh,
                                                const int* __restrict__ src,
                                                const int* __restrict__ tgt,
                                                float* __restrict__ recon, int E) {
    int g = (blockIdx.x * 256 + threadIdx.x) >> 2;
    int fl = threadIdx.x & 3;
    int e0 = g * 4;
    if (e0 >= E) return;
    int cnt = min(4, E - e0);
    int s[4], t[4];
#pragma unroll
    for (int q = 0; q < 4; q++) {
        int e = (q < cnt) ? e0 + q : e0;
        s[q] = src[e];
        t[q] = tgt[e];
    }
    uint4 Za[4], Zb[4];
#pragma unroll
    for (int q = 0; q < 4; q++) {
        Za[q] = *(const uint4*)(zh + (size_t)s[q] * 32 + fl * 8);
        Zb[q] = *(const uint4*)(zh + (size_t)t[q] * 32 + fl * 8);
    }
    float v[4];
#pragma unroll
    for (int q = 0; q < 4; q++) {
        float x = bfdot8(Za[q], Zb[q]);
        x += __shfl_xor(x, 1);
        x += __shfl_xor(x, 2);
        v[q] = x;
    }
    if (fl == 0) {
        if (cnt == 4) {
            *(float4*)(recon + e0) = make_float4(v[0], v[1], v[2], v[3]);
        } else {
            for (int q = 0; q < cnt; q++) recon[e0 + q] = v[q];
        }
    }
}

extern "C" void kernel_launch(void* const* d_in, const int* in_sizes, int n_in,
                              void* d_out, int out_size, void* d_ws, size_t ws_size,
                              hipStream_t stream) {
    const float* x = (const float*)d_in[0];
    const float* W1 = (const float*)d_in[1];
    const float* b1 = (const float*)d_in[2];
    const float* W2 = (const float*)d_in[3];
    const float* b2 = (const float*)d_in[4];
    const int* ei = (const int*)d_in[5];

    int N = in_sizes[0] / 128;
    int E = in_sizes[5] / 2;
    const int* src = ei;
    const int* tgt = ei + E;
    int NB = divup(N, BNODES);

    char* ws = (char*)d_ws;
    size_t off = 0;
    auto alloc = [&](size_t bytes) {
        size_t r = off;
        off += (bytes + 255) & ~(size_t)255;
        return r;
    };
    int* gcur = (int*)(ws + alloc(NBMAX * 4));
    unsigned* ebuf = (unsigned*)(ws + alloc((size_t)NB * CAP * 4));
    int* col = (int*)(ws + alloc((size_t)NB * CAP * 4));
    int* rowbeg = (int*)(ws + alloc((size_t)N * 4));
    int* rowend = (int*)(ws + alloc((size_t)N * 4));
    float* dinv = (float*)(ws + alloc((size_t)N * 4));
    __half* hs = (__half*)(ws + alloc((size_t)(N + 1) * 64 * 2));   // +pad row n
    __half* zs = (__half*)(ws + alloc((size_t)(N + 1) * 32 * 2));   // +pad row n
    unsigned short* zh = (unsigned short*)(ws + alloc((size_t)N * 32 * 2));

    float* zout = (float*)d_out;
    float* recon = zout + (size_t)N * 32;

    k_init<<<1, 256, 0, stream>>>(gcur, (unsigned*)(hs + (size_t)N * 64),
                                  (unsigned*)(zs + (size_t)N * 32));
    k_part<<<divup(E, CHF), 512, 0, stream>>>(src, tgt, gcur, ebuf, E, NB);
    k_bfill<<<NB, BNODES, 0, stream>>>(ebuf, gcur, rowbeg, rowend, col, dinv, N);

    k_mm1<<<divup(N, 128), 512, 0, stream>>>(x, W1, dinv, hs, N);
    k_conv1mm2<<<divup(N, 16), 256, 0, stream>>>(hs, rowbeg, rowend, col, dinv,
                                                 b1, W2, zs, N);
    k_conv2<<<divup(N, 16), 256, 0, stream>>>(zs, rowbeg, rowend, col, dinv, b2, zout, zh, N);
    k_decode<<<divup(E, 256), 256, 0, stream>>>(zh, src, tgt, recon, E);
}

// Round 10
// 221.648 us; speedup vs baseline: 2.9898x; 1.0078x over previous
//
#include <hip/hip_runtime.h>
#include <hip/hip_fp16.h>
#include <math.h>

// GAE: 2x GCNConv + edge dot decode.
// R1-R10: bucketed CSR build, fp16 tables, wide gathers, MFMA mms,
//         4 nodes/wave gather convs.  (best: 228.2us)
// R11 FAILED: LDS decode latency-bound. R12/R14 NEUTRAL: build reshapes.
// R13/R15 MEASUREMENT: warm kernel ledger ~100us; per-dispatch gap ~3-5us;
//      in-region re-poison fill ~42us (untouchable).
// R16 (226.2us): mm1 A-fragments direct global->reg.
// R17 BIG FAIL (662us): cooperative grid.sync ~100us each on 8 XCDs.
// R18 REGRESSED (231.2us): bfill+mm1 fusion degraded mm1 geometry.
// R19 WIN (223.4us): mm2 fused into conv1's epilogue (block = one MFMA
//      16-row tile; h2 via LDS, never global). -1 dispatch, -25.6MB.
// R20: branchless 32-edge path + load hoisting in both convs. Mean deg~17
//      means ~90% of waves execute the deg>16 branch anyway; making it
//      unconditional (invalid slots -> cached zero pad row; fp16 +0 is
//      exact identity, acc can never be -0) lets all 8 loads per batch
//      issue before any accumulation -> 2x memory-level parallelism in
//      the latency-bound gathers. Accumulation sequence unchanged ->
//      bit-identical outputs.

#define NBMAX 512    // max buckets (supports N <= 131072 at 256/bucket)
#define BSHIFT 8     // 256 nodes per bucket
#define BNODES 256
#define CHF 16384    // edges per partition block (98 at E=1.6M)
#define CAPSHIFT 13  // 8192 edge slots per bucket
#define CAP (1 << CAPSHIFT)

typedef _Float16 half8 __attribute__((ext_vector_type(8)));
typedef float floatx4 __attribute__((ext_vector_type(4)));

static inline int divup(int a, int b) { return (a + b - 1) / b; }

__device__ inline void acc8(__half2* a, float4 v) {
    const __half2* h = (const __half2*)&v;
    a[0] = __hadd2(a[0], h[0]);
    a[1] = __hadd2(a[1], h[1]);
    a[2] = __hadd2(a[2], h[2]);
    a[3] = __hadd2(a[3], h[3]);
}
__device__ inline unsigned short f2bf(float f) {
    unsigned u = __builtin_bit_cast(unsigned, f);
    u = (u + 0x7FFFu + ((u >> 16) & 1u)) >> 16;
    return (unsigned short)u;
}

// ---- init bucket cursors + zero pad rows ------------------------------------

__global__ void k_init(int* __restrict__ gcur, unsigned* __restrict__ hs_pad,
                       unsigned* __restrict__ zs_pad) {
    int t = threadIdx.x;
    for (int b = t; b < NBMAX; b += 256) gcur[b] = b << CAPSHIFT;
    if (t < 32) hs_pad[t] = 0;            // 128B zero row (64 fp16)
    else if (t < 48) zs_pad[t - 32] = 0;  // 64B zero row (32 fp16)
}

// ---- partition edges into fixed-capacity buckets (two-pass) -----------------
// ebuf word: (local_tgt << 23) | src   (src < 2^23, local_tgt < 256)

__global__ __launch_bounds__(512) void k_part(const int* __restrict__ src,
                                              const int* __restrict__ tgt,
                                              int* __restrict__ gcur,
                                              unsigned* __restrict__ ebuf, int E, int NB) {
    __shared__ int h[NBMAX];
    __shared__ int base[NBMAX];
    int tid = threadIdx.x;
    int e0 = blockIdx.x * CHF;
    for (int b = tid; b < NB; b += 512) h[b] = 0;
    __syncthreads();
#pragma unroll
    for (int r = 0; r < 8; r++) {
        int e = e0 + (r * 512 + tid) * 4;
        if (e + 3 < E) {
            int4 t4 = *(const int4*)(tgt + e);
            atomicAdd(&h[t4.x >> BSHIFT], 1);
            atomicAdd(&h[t4.y >> BSHIFT], 1);
            atomicAdd(&h[t4.z >> BSHIFT], 1);
            atomicAdd(&h[t4.w >> BSHIFT], 1);
        } else {
            for (int j = 0; j < 4; j++) {
                int ee = e + j;
                if (ee < E) atomicAdd(&h[tgt[ee] >> BSHIFT], 1);
            }
        }
    }
    __syncthreads();
    for (int b = tid; b < NB; b += 512) {
        int c = h[b];
        base[b] = c ? atomicAdd(&gcur[b], c) : 0;
    }
    __syncthreads();
#pragma unroll
    for (int r = 0; r < 8; r++) {
        int e = e0 + (r * 512 + tid) * 4;
        if (e + 3 < E) {
            int4 t4 = *(const int4*)(tgt + e);
            int4 s4 = *(const int4*)(src + e);
            int tv[4] = {t4.x, t4.y, t4.z, t4.w};
            int sw[4] = {s4.x, s4.y, s4.z, s4.w};
#pragma unroll
            for (int j = 0; j < 4; j++) {
                int t = tv[j];
                int pos = atomicAdd(&base[t >> BSHIFT], 1);
                ebuf[pos] = ((unsigned)(t & (BNODES - 1)) << 23) | (unsigned)sw[j];
            }
        } else {
            for (int j = 0; j < 4; j++) {
                int ee = e + j;
                if (ee < E) {
                    int t = tgt[ee];
                    int pos = atomicAdd(&base[t >> BSHIFT], 1);
                    ebuf[pos] = ((unsigned)(t & (BNODES - 1)) << 23) | (unsigned)src[ee];
                }
            }
        }
    }
}

// ---- per-bucket CSR fill: LDS count/scan/cursor -----------------------------

__global__ __launch_bounds__(256) void k_bfill(const unsigned* __restrict__ ebuf,
                                               const int* __restrict__ gcur,
                                               int* __restrict__ rowbeg,
                                               int* __restrict__ rowend,
                                               int* __restrict__ col,
                                               float* __restrict__ dinv, int n) {
    __shared__ int s_cnt[BNODES];
    __shared__ int s_scan[BNODES];
    __shared__ int s_cur[BNODES];
    int b = blockIdx.x, tid = threadIdx.x;
    int nbase = b << BSHIFT;
    int ebase = b << CAPSHIFT;
    int eend = gcur[b];
    s_cnt[tid] = 0;
    __syncthreads();
    for (int e = ebase + tid; e < eend; e += BNODES) {
        atomicAdd(&s_cnt[ebuf[e] >> 23], 1);
    }
    __syncthreads();
    s_scan[tid] = s_cnt[tid];
    __syncthreads();
    for (int off = 1; off < BNODES; off <<= 1) {
        int t = (tid >= off) ? s_scan[tid - off] : 0;
        __syncthreads();
        s_scan[tid] += t;
        __syncthreads();
    }
    int excl = s_scan[tid] - s_cnt[tid];
    s_cur[tid] = excl;
    int node = nbase + tid;
    if (node < n) {
        rowbeg[node] = ebase + excl;
        rowend[node] = ebase + excl + s_cnt[tid];
        dinv[node] = rsqrtf((float)(s_cnt[tid] + 1));  // +1 self-loop
    }
    __syncthreads();
    for (int e = ebase + tid; e < eend; e += BNODES) {
        unsigned p = ebuf[e];
        int pos = atomicAdd(&s_cur[p >> 23], 1);
        col[ebase + pos] = (int)(p & 0x7FFFFFu);
    }
}

// ---- matmul 1 (MFMA): hs[n][j] = fp16((x[n] @ W1[:,j]) * dinv[n]) -----------
// R16 form: A-fragments direct global->reg; Wt1 in LDS; 512 thr, 128 nodes.

__global__ __launch_bounds__(512) void k_mm1(const float* __restrict__ x,
                                             const float* __restrict__ W1,
                                             const float* __restrict__ dinv,
                                             __half* __restrict__ hs, int n) {
    __shared__ _Float16 Wt[64 * 136];  // [col][k] (transposed)
    int tid = threadIdx.x;
    int nbase = blockIdx.x * 128;
#pragma unroll
    for (int i = 0; i < 8; i++) {
        int f = tid + i * 512;          // 0..4095
        int c = f & 63, kp = f >> 6;    // kp 0..63 (pairs of k)
        float a = W1[(size_t)(2 * kp) * 64 + c];
        float b = W1[(size_t)(2 * kp + 1) * 64 + c];
        *(__half2*)&Wt[c * 136 + 2 * kp] = __floats2half2_rn(a, b);
    }
    __syncthreads();
    int w = tid >> 6, lane = tid & 63;
    int quad = lane >> 4, m = lane & 15;
    int arow = nbase + w * 16 + m;
    const float* xb = x + (size_t)min(arow, n - 1) * 128;  // clamped row
    floatx4 acc[4] = {{0.f, 0.f, 0.f, 0.f}, {0.f, 0.f, 0.f, 0.f},
                      {0.f, 0.f, 0.f, 0.f}, {0.f, 0.f, 0.f, 0.f}};
#pragma unroll
    for (int kt = 0; kt < 4; kt++) {
        float4 v0 = *(const float4*)(xb + kt * 32 + quad * 8);
        float4 v1 = *(const float4*)(xb + kt * 32 + quad * 8 + 4);
        union { half8 h8; __half2 h2[4]; } ua;
        ua.h2[0] = __floats2half2_rn(v0.x, v0.y);
        ua.h2[1] = __floats2half2_rn(v0.z, v0.w);
        ua.h2[2] = __floats2half2_rn(v1.x, v1.y);
        ua.h2[3] = __floats2half2_rn(v1.z, v1.w);
#pragma unroll
        for (int ct = 0; ct < 4; ct++) {
            half8 b = *(const half8*)&Wt[(ct * 16 + m) * 136 + kt * 32 + quad * 8];
            acc[ct] = __builtin_amdgcn_mfma_f32_16x16x32_f16(ua.h8, b, acc[ct], 0, 0, 0);
        }
    }
#pragma unroll
    for (int reg = 0; reg < 4; reg++) {
        int node = nbase + w * 16 + quad * 4 + reg;
        if (node < n) {
            float d = dinv[node];
#pragma unroll
            for (int ct = 0; ct < 4; ct++) {
                hs[(size_t)node * 64 + ct * 16 + m] = __float2half(acc[ct][reg] * d);
            }
        }
    }
}

// ---- conv1 + mm2 fused ------------------------------------------------------
// conv1: 4 nodes/wave (16-lane quarters), 8 feat lanes x 2 edge slots.
// R20: branchless 32-edge path -- all 8 loads per 16-edge batch issued
// before accumulation; invalid slots read the cached zero pad row (+0 add
// is exact identity). Same acc8 sequence -> bit-identical h2.
// Block's 16 nodes = one MFMA 16-row tile; h2 -> pitch-72 LDS; wave 0 runs
// k_mm2's exact MFMA sequence -> bit-identical zs.

__global__ __launch_bounds__(256) void k_conv1mm2(const __half* __restrict__ hs,
                                                  const int* __restrict__ rowbeg,
                                                  const int* __restrict__ rowend,
                                                  const int* __restrict__ col,
                                                  const float* __restrict__ dinv,
                                                  const float* __restrict__ b1,
                                                  const float* __restrict__ W2,
                                                  __half* __restrict__ zs, int n) {
    __shared__ _Float16 Wt[32 * 72];   // transposed W2, fp16 (as in k_mm2)
    __shared__ _Float16 h2s[16 * 72];  // block's 16 h2 rows, pitch 72 (bank-clean)
    int tid = threadIdx.x;
    // stage Wt2 (identical to k_mm2's staging)
#pragma unroll
    for (int i = 0; i < 4; i++) {
        int f = tid + i * 256;          // 0..1023
        int c = f & 31, kp = f >> 5;    // kp 0..31
        float a = W2[(size_t)(2 * kp) * 32 + c];
        float b = W2[(size_t)(2 * kp + 1) * 32 + c];
        *(__half2*)&Wt[c * 72 + 2 * kp] = __floats2half2_rn(a, b);
    }

    int gw = (blockIdx.x * 256 + tid) >> 6;
    int lane = tid & 63;
    int q = lane >> 4, ln = lane & 15;
    int w = gw * 4 + q;
    int qb = q << 4;
    int el = ln >> 3, fl = ln & 7;  // 2 edge slots x 8 feat lanes
    if (w < n) {
        int beg = rowbeg[w], end = rowend[w];
        int deg = end - beg;
        int m = min(16, deg);
        int m2 = min(16, deg - 16);  // may be <=0
        int sl = (ln < m) ? col[beg + ln] : 0;
        int sl2 = (ln < m2) ? col[beg + 16 + ln] : 0;
        __half2 a2[4];
#pragma unroll
        for (int j = 0; j < 4; j++) a2[j] = __half2half2(__float2half(0.f));
        // batch A: self + edges 0..15 (all 9 loads in flight)
        int rs = (el == 0) ? w : n;
        float4 S = *(const float4*)(hs + (size_t)rs * 64 + fl * 8);
        float4 L[8];
#pragma unroll
        for (int r = 0; r < 4; r++) {
            int idx = 2 * r + el;
            int s = __shfl(sl, qb + idx);
            int a = (idx < m) ? s : n;
            L[r] = *(const float4*)(hs + (size_t)a * 64 + fl * 8);
        }
#pragma unroll
        for (int r = 0; r < 4; r++) {
            int idx = 8 + 2 * r + el;
            int s = __shfl(sl, qb + idx);
            int a = (idx < m) ? s : n;
            L[4 + r] = *(const float4*)(hs + (size_t)a * 64 + fl * 8);
        }
        acc8(a2, S);
#pragma unroll
        for (int r = 0; r < 8; r++) acc8(a2, L[r]);
        // batch B: edges 16..31, unconditional (invalid -> zero pad row)
#pragma unroll
        for (int r = 0; r < 4; r++) {
            int idx = 2 * r + el;
            int s = __shfl(sl2, qb + idx);
            int a = (idx < m2) ? s : n;
            L[r] = *(const float4*)(hs + (size_t)a * 64 + fl * 8);
        }
#pragma unroll
        for (int r = 0; r < 4; r++) {
            int idx = 8 + 2 * r + el;
            int s = __shfl(sl2, qb + idx);
            int a = (idx < m2) ? s : n;
            L[4 + r] = *(const float4*)(hs + (size_t)a * 64 + fl * 8);
        }
#pragma unroll
        for (int r = 0; r < 8; r++) acc8(a2, L[r]);
        if (deg > 32) {  // rare (~0.01%)
            for (int b0 = 32; b0 < deg; b0 += 16) {
                int mc = min(16, deg - b0);
                int sl3 = (ln < mc) ? col[beg + b0 + ln] : 0;
                for (int r = 0; r < 8; r++) {
                    int idx = 2 * r + el;
                    int s = __shfl(sl3, qb + idx);
                    int a = (idx < mc) ? s : n;
                    float4 v = *(const float4*)(hs + (size_t)a * 64 + fl * 8);
                    acc8(a2, v);
                }
            }
        }
        // fp32 reduction over the 2 el groups (d=8, intra-quarter)
        float r[8];
#pragma unroll
        for (int j = 0; j < 4; j++) {
            float2 f = __half22float2(a2[j]);
            r[2 * j] = f.x;
            r[2 * j + 1] = f.y;
        }
#pragma unroll
        for (int j = 0; j < 8; j++) r[j] += __shfl_xor(r[j], 8);

        if (el == 0) {
            float d = dinv[w];
            float4 bb0 = *(const float4*)(b1 + fl * 8);
            float4 bb1 = *(const float4*)(b1 + fl * 8 + 4);
            union { float4 f; __half2 h[4]; } u;
            u.h[0] = __floats2half2_rn(fmaxf(r[0] * d + bb0.x, 0.f),
                                       fmaxf(r[1] * d + bb0.y, 0.f));
            u.h[1] = __floats2half2_rn(fmaxf(r[2] * d + bb0.z, 0.f),
                                       fmaxf(r[3] * d + bb0.w, 0.f));
            u.h[2] = __floats2half2_rn(fmaxf(r[4] * d + bb1.x, 0.f),
                                       fmaxf(r[5] * d + bb1.y, 0.f));
            u.h[3] = __floats2half2_rn(fmaxf(r[6] * d + bb1.z, 0.f),
                                       fmaxf(r[7] * d + bb1.w, 0.f));
            *(float4*)&h2s[(w & 15) * 72 + fl * 8] = u.f;  // block-local row
        }
    }
    __syncthreads();

    // mm2 phase: wave 0 computes zs for the block's 16 nodes (= 1 row tile).
    if (tid < 64) {
        int quad = tid >> 4, m = tid & 15;
        int nbase = blockIdx.x * 16;
        floatx4 acc[2] = {{0.f, 0.f, 0.f, 0.f}, {0.f, 0.f, 0.f, 0.f}};
#pragma unroll
        for (int kt = 0; kt < 2; kt++) {
            half8 a = *(const half8*)&h2s[m * 72 + kt * 32 + quad * 8];
#pragma unroll
            for (int ct = 0; ct < 2; ct++) {
                half8 b = *(const half8*)&Wt[(ct * 16 + m) * 72 + kt * 32 + quad * 8];
                acc[ct] = __builtin_amdgcn_mfma_f32_16x16x32_f16(a, b, acc[ct], 0, 0, 0);
            }
        }
#pragma unroll
        for (int reg = 0; reg < 4; reg++) {
            int node = nbase + quad * 4 + reg;
            if (node < n) {
                float d = dinv[node];
#pragma unroll
                for (int ct = 0; ct < 2; ct++) {
                    zs[(size_t)node * 32 + ct * 16 + m] = __float2half(acc[ct][reg] * d);
                }
            }
        }
    }
}

// ---- conv2: 4 nodes/wave (16-lane quarters), 4 feat lanes x 4 edge slots ----
// R20: branchless -- both 4-load batches (edges 0..15 and 16..31) issued
// before accumulation; invalid slots read the zero pad row. zs pad row at
// index n. bf16 zh epilogue for decode.

__global__ __launch_bounds__(256) void k_conv2(const __half* __restrict__ zs,
                                               const int* __restrict__ rowbeg,
                                               const int* __restrict__ rowend,
                                               const int* __restrict__ col,
                                               const float* __restrict__ dinv,
                                               const float* __restrict__ b2,
                                               float* __restrict__ zout,
                                               unsigned short* __restrict__ zh, int n) {
    int gw = (blockIdx.x * 256 + threadIdx.x) >> 6;
    int lane = threadIdx.x & 63;
    int q = lane >> 4, ln = lane & 15;
    int w = gw * 4 + q;
    if (w >= n) return;
    int qb = q << 4;
    int el = ln >> 2, fl = ln & 3;  // 4 edge slots x 4 feat lanes
    int beg = rowbeg[w], end = rowend[w];
    int deg = end - beg;
    int m = min(16, deg);
    int m2 = min(16, deg - 16);
    int sl = (ln < m) ? col[beg + ln] : 0;
    int sl2 = (ln < m2) ? col[beg + 16 + ln] : 0;
    __half2 a2[4];
#pragma unroll
    for (int j = 0; j < 4; j++) a2[j] = __half2half2(__float2half(0.f));
    int rs = (el == 0) ? w : n;
    float4 S = *(const float4*)(zs + (size_t)rs * 32 + fl * 8);
    float4 L[8];
#pragma unroll
    for (int r = 0; r < 4; r++) {  // edges 0..15
        int idx = 4 * r + el;
        int s = __shfl(sl, qb + idx);
        int a = (idx < m) ? s : n;
        L[r] = *(const float4*)(zs + (size_t)a * 32 + fl * 8);
    }
#pragma unroll
    for (int r = 0; r < 4; r++) {  // edges 16..31, unconditional
        int idx = 4 * r + el;
        int s = __shfl(sl2, qb + idx);
        int a = (idx < m2) ? s : n;
        L[4 + r] = *(const float4*)(zs + (size_t)a * 32 + fl * 8);
    }
    acc8(a2, S);
#pragma unroll
    for (int r = 0; r < 8; r++) acc8(a2, L[r]);
    if (deg > 32) {  // rare
        for (int b0 = 32; b0 < deg; b0 += 16) {
            int mc = min(16, deg - b0);
            int sl3 = (ln < mc) ? col[beg + b0 + ln] : 0;
            for (int r = 0; r < 4; r++) {
                int idx = 4 * r + el;
                int s = __shfl(sl3, qb + idx);
                int a = (idx < mc) ? s : n;
                float4 v = *(const float4*)(zs + (size_t)a * 32 + fl * 8);
                acc8(a2, v);
            }
        }
    }
    // fp32 reduction over the 4 el groups (d=4,8 intra-quarter)
    float r[8];
#pragma unroll
    for (int j = 0; j < 4; j++) {
        float2 f = __half22float2(a2[j]);
        r[2 * j] = f.x;
        r[2 * j + 1] = f.y;
    }
#pragma unroll
    for (int d = 4; d < 16; d <<= 1)
#pragma unroll
        for (int j = 0; j < 8; j++) r[j] += __shfl_xor(r[j], d);

    if (el == 0) {  // lanes fl=0..3 of each quarter, 8 feats each
        float d = dinv[w];
        float4 bb0 = *(const float4*)(b2 + fl * 8);
        float4 bb1 = *(const float4*)(b2 + fl * 8 + 4);
        float o0 = r[0] * d + bb0.x, o1 = r[1] * d + bb0.y;
        float o2 = r[2] * d + bb0.z, o3 = r[3] * d + bb0.w;
        float o4 = r[4] * d + bb1.x, o5 = r[5] * d + bb1.y;
        float o6 = r[6] * d + bb1.z, o7 = r[7] * d + bb1.w;
        *(float4*)(zout + (size_t)w * 32 + fl * 8) = make_float4(o0, o1, o2, o3);
        *(float4*)(zout + (size_t)w * 32 + fl * 8 + 4) = make_float4(o4, o5, o6, o7);
        uint4 p;
        p.x = (unsigned)f2bf(o0) | ((unsigned)f2bf(o1) << 16);
        p.y = (unsigned)f2bf(o2) | ((unsigned)f2bf(o3) << 16);
        p.z = (unsigned)f2bf(o4) | ((unsigned)f2bf(o5) << 16);
        p.w = (unsigned)f2bf(o6) | ((unsigned)f2bf(o7) << 16);
        *(uint4*)(zh + (size_t)w * 32 + fl * 8) = p;
    }
}

// ---- decode: bf16 rows (64B), 4 lanes/edge, 4 edges per group ---------------
// zh is 6.4MB -> L2/L3-resident; 8 independent uint4 loads per group give the
// MLP that makes this latency-tolerant (R11 lesson: do not serialize).

__device__ inline float bfdot8(uint4 a, uint4 b) {
    const unsigned* pa = (const unsigned*)&a;
    const unsigned* pb = (const unsigned*)&b;
    float v = 0.f;
#pragma unroll
    for (int w = 0; w < 4; w++) {
        float alo = __builtin_bit_cast(float, pa[w] << 16);
        float ahi = __builtin_bit_cast(float, pa[w] & 0xFFFF0000u);
        float blo = __builtin_bit_cast(float, pb[w] << 16);
        float bhi = __builtin_bit_cast(float, pb[w] & 0xFFFF0000u);
        v += alo * blo + ahi * bhi;
    }
    return v;
}

__global__ __launch_bounds__(256) void k_decode(const unsigned short* __restrict__ zh,
                                                const int* __restrict__ src,
                                                const int* __restrict__ tgt,
                                                float* __restrict__ recon, int E) {
    int g = (blockIdx.x * 256 + threadIdx.x) >> 2;
    int fl = threadIdx.x & 3;
    int e0 = g * 4;
    if (e0 >= E) return;
    int cnt = min(4, E - e0);
    int s[4], t[4];
#pragma unroll
    for (int q = 0; q < 4; q++) {
        int e = (q < cnt) ? e0 + q : e0;
        s[q] = src[e];
        t[q] = tgt[e];
    }
    uint4 Za[4], Zb[4];
#pragma unroll
    for (int q = 0; q < 4; q++) {
        Za[q] = *(const uint4*)(zh + (size_t)s[q] * 32 + fl * 8);
        Zb[q] = *(const uint4*)(zh + (size_t)t[q] * 32 + fl * 8);
    }
    float v[4];
#pragma unroll
    for (int q = 0; q < 4; q++) {
        float x = bfdot8(Za[q], Zb[q]);
        x += __shfl_xor(x, 1);
        x += __shfl_xor(x, 2);
        v[q] = x;
    }
    if (fl == 0) {
        if (cnt == 4) {
            *(float4*)(recon + e0) = make_float4(v[0], v[1], v[2], v[3]);
        } else {
            for (int q = 0; q < cnt; q++) recon[e0 + q] = v[q];
        }
    }
}

extern "C" void kernel_launch(void* const* d_in, const int* in_sizes, int n_in,
                              void* d_out, int out_size, void* d_ws, size_t ws_size,
                              hipStream_t stream) {
    const float* x = (const float*)d_in[0];
    const float* W1 = (const float*)d_in[1];
    const float* b1 = (const float*)d_in[2];
    const float* W2 = (const float*)d_in[3];
    const float* b2 = (const float*)d_in[4];
    const int* ei = (const int*)d_in[5];

    int N = in_sizes[0] / 128;
    int E = in_sizes[5] / 2;
    const int* src = ei;
    const int* tgt = ei + E;
    int NB = divup(N, BNODES);

    char* ws = (char*)d_ws;
    size_t off = 0;
    auto alloc = [&](size_t bytes) {
        size_t r = off;
        off += (bytes + 255) & ~(size_t)255;
        return r;
    };
    int* gcur = (int*)(ws + alloc(NBMAX * 4));
    unsigned* ebuf = (unsigned*)(ws + alloc((size_t)NB * CAP * 4));
    int* col = (int*)(ws + alloc((size_t)NB * CAP * 4));
    int* rowbeg = (int*)(ws + alloc((size_t)N * 4));
    int* rowend = (int*)(ws + alloc((size_t)N * 4));
    float* dinv = (float*)(ws + alloc((size_t)N * 4));
    __half* hs = (__half*)(ws + alloc((size_t)(N + 1) * 64 * 2));   // +pad row n
    __half* zs = (__half*)(ws + alloc((size_t)(N + 1) * 32 * 2));   // +pad row n
    unsigned short* zh = (unsigned short*)(ws + alloc((size_t)N * 32 * 2));

    float* zout = (float*)d_out;
    float* recon = zout + (size_t)N * 32;

    k_init<<<1, 256, 0, stream>>>(gcur, (unsigned*)(hs + (size_t)N * 64),
                                  (unsigned*)(zs + (size_t)N * 32));
    k_part<<<divup(E, CHF), 512, 0, stream>>>(src, tgt, gcur, ebuf, E, NB);
    k_bfill<<<NB, BNODES, 0, stream>>>(ebuf, gcur, rowbeg, rowend, col, dinv, N);

    k_mm1<<<divup(N, 128), 512, 0, stream>>>(x, W1, dinv, hs, N);
    k_conv1mm2<<<divup(N, 16), 256, 0, stream>>>(hs, rowbeg, rowend, col, dinv,
                                                 b1, W2, zs, N);
    k_conv2<<<divup(N, 16), 256, 0, stream>>>(zs, rowbeg, rowend, col, dinv, b2, zout, zh, N);
    k_decode<<<divup(E, 256), 256, 0, stream>>>(zh, src, tgt, recon, E);
}